// Round 8
// baseline (6794.291 us; speedup 1.0000x reference)
//
#include <hip/hip_runtime.h>
#include <stdint.h>

// Persistent dataflow 2-layer LSTM, MI355X (gfx950).
// 64 WGs x 256 thr: WGs 0..31 = layer0 (16 h-cols each), 32..63 = layer1.
// Round-11: direct-to-register h loads on the critical chain.
// r7 counters: 92% of the 9.3k-cy step is latency (MFMA 272cy + VALU 483cy
// busy). The h LDS staging hop (DMA -> vmcnt(0) -> barrier -> ds_read)
// existed only to share the tile across waves; each lane's MFMA fragments
// sit at fixed ring offsets, so lanes now global_load_dwordx4 their OWN
// fragments (write-once addresses -> L2 miss -> MALL, same coherence as the
// verified DMA path). Removes DMA latency + vmcnt(0) + one barrier from
// both layers' chains. L1 additionally issues the h1 loads BEFORE the
// h0-part LDS MFMAs so the h0 work hides under the h1 load round trip.
// VGPR grows ~128 (free: 1 WG/CU -> 1 wave/SIMD -> up to 512 VGPR).
// x path (L0) and h0 prefetch (L1) stay LDS-staged (off-chain).
// Sync semantics byte-identical r3. Accumulation order unchanged.
// HANG-PROOF: per-thread global spin budget; on exhaustion waits no-op.

#define SEQ   1024
#define NB    32
#define HID   512
#define NWG   64
#define L0WGS 32
#define FSTRIDE 16                // flag words per step (64B line, 32 bytes used)
#define SPIN_BUDGET (1 << 20)
#define ROWB  1040                // LDS row stride: 1024 data + 16 pad
#define SMEM_MISC 11776           // sizeof(Shared) with 18-float rows
#define SMEM_BYTES (SMEM_MISC + 2 * 32 * ROWB)   // 78336

typedef __attribute__((ext_vector_type(8))) short s16x8;
typedef __attribute__((ext_vector_type(4))) float f32x4;

__device__ __forceinline__ uint16_t f2bf(float x) {
    uint32_t u = __float_as_uint(x);
    return (uint16_t)((u + 0x7FFFu + ((u >> 16) & 1u)) >> 16);
}
__device__ __forceinline__ uint32_t pack2bf(float a, float b) {
    return (uint32_t)f2bf(a) | ((uint32_t)f2bf(b) << 16);
}
__device__ __forceinline__ s16x8 pack8(const float* p) {
    float4 a = *(const float4*)p;
    float4 b = *(const float4*)(p + 4);
    s16x8 r;
    r[0] = (short)f2bf(a.x); r[1] = (short)f2bf(a.y);
    r[2] = (short)f2bf(a.z); r[3] = (short)f2bf(a.w);
    r[4] = (short)f2bf(b.x); r[5] = (short)f2bf(b.y);
    r[6] = (short)f2bf(b.z); r[7] = (short)f2bf(b.w);
    return r;
}
__device__ __forceinline__ f32x4 mfma16(s16x8 a, s16x8 b, f32x4 c) {
    return __builtin_amdgcn_mfma_f32_16x16x32_bf16(a, b, c, 0, 0, 0);
}
__device__ __forceinline__ float sigm(float x) { return 1.0f / (1.0f + __expf(-x)); }
__device__ __forceinline__ float tanh_(float x) { return 1.0f - 2.0f / (__expf(2.0f * x) + 1.0f); }

__device__ __forceinline__ void st_u32(uint32_t* p, uint32_t v) {
    __hip_atomic_store(p, v, __ATOMIC_RELAXED, __HIP_MEMORY_SCOPE_AGENT);
}
__device__ __forceinline__ void st_u64(uint64_t* p, uint64_t v) {
    __hip_atomic_store(p, v, __ATOMIC_RELAXED, __HIP_MEMORY_SCOPE_AGENT);
}
__device__ __forceinline__ void st_u8(uint8_t* p, uint8_t v) {
    __hip_atomic_store(p, v, __ATOMIC_RELAXED, __HIP_MEMORY_SCOPE_AGENT);
}
__device__ __forceinline__ unsigned ld_flag(const unsigned* p) {
    return __hip_atomic_load(p, __ATOMIC_RELAXED, __HIP_MEMORY_SCOPE_AGENT);
}
// Wait until all 32 producer bytes in the 64B step slot are 1.
// Lanes 0..7 each load one dword of the line (one coalesced request/wave).
__device__ __forceinline__ void poll_all32(const unsigned* p, int& budget) {
    const int lane = threadIdx.x & 63;
    for (;;) {
        bool ok = (lane >= 8) || (ld_flag(p + lane) == 0x01010101u);
        if (__all(ok)) break;
        if (--budget < 0) break;          // hang-proof: give up, free-run
        __builtin_amdgcn_s_sleep(1);
    }
    asm volatile("" ::: "memory");        // ring reads stay below the poll
}

// Async global->LDS DMA, 16B/lane. LDS dest = wave-uniform base + lane*16.
__device__ __forceinline__ void dma16(const void* g, void* l) {
    __builtin_amdgcn_global_load_lds(
        (const __attribute__((address_space(1))) unsigned int*)g,
        (__attribute__((address_space(3))) unsigned int*)l, 16, 0, 0);
}
// Stage 32 rows of 1024B into LDS rows of stride ROWB; wave wv does 8 rows.
__device__ __forceinline__ void stage32(const char* gbase, size_t gstride,
                                        char* lbase, int lane, int wv) {
#pragma unroll
    for (int i = 0; i < 8; ++i) {
        const int r = wv * 8 + i;
        dma16(gbase + (size_t)r * gstride + (size_t)lane * 16, lbase + r * ROWB);
    }
}

struct Shared {
    float gbuf[4][NB][18];    // 18-float rows
    float cbuf[NB][18];
    float bbuf[4][16];
};

__device__ __forceinline__ void load_bias_c(Shared& sh,
        const float* bf_, const float* bi_, const float* bc_, const float* bo_,
        int col0) {
    const int tid = threadIdx.x;
    if (tid < 16)       sh.bbuf[0][tid]      = bf_[col0 + tid];
    else if (tid < 32)  sh.bbuf[1][tid - 16] = bi_[col0 + tid - 16];
    else if (tid < 48)  sh.bbuf[2][tid - 32] = bc_[col0 + tid - 32];
    else if (tid < 64)  sh.bbuf[3][tid - 48] = bo_[col0 + tid - 48];
    float2 z = make_float2(0.f, 0.f);
    ((float2*)sh.cbuf)[tid] = z;                       // 576 floats = 288 f2
    if (tid < 32) ((float2*)sh.cbuf)[256 + tid] = z;
}

__device__ __forceinline__ float2 gates2(Shared& sh, int b, int n) {
    float2 pf = *(float2*)&sh.gbuf[0][b][n];
    float2 pi = *(float2*)&sh.gbuf[1][b][n];
    float2 pc = *(float2*)&sh.gbuf[2][b][n];
    float2 po = *(float2*)&sh.gbuf[3][b][n];
    float2 h;
    {
        float f = sigm(pf.x + sh.bbuf[0][n]);
        float i = sigm(pi.x + sh.bbuf[1][n]);
        float g = tanh_(pc.x + sh.bbuf[2][n]);
        float o = sigm(po.x + sh.bbuf[3][n]);
        float c = f * sh.cbuf[b][n] + i * g;
        sh.cbuf[b][n] = c;
        h.x = o * tanh_(c);
    }
    {
        float f = sigm(pf.y + sh.bbuf[0][n + 1]);
        float i = sigm(pi.y + sh.bbuf[1][n + 1]);
        float g = tanh_(pc.y + sh.bbuf[2][n + 1]);
        float o = sigm(po.y + sh.bbuf[3][n + 1]);
        float c = f * sh.cbuf[b][n + 1] + i * g;
        sh.cbuf[b][n + 1] = c;
        h.y = o * tanh_(c);
    }
    return h;
}

extern __shared__ char smem[];

__device__ void body_l0(const float* __restrict__ xg,
                        const float* __restrict__ Wf, const float* __restrict__ Wi,
                        const float* __restrict__ Wc, const float* __restrict__ Wo,
                        const float* __restrict__ bf_, const float* __restrict__ bi_,
                        const float* __restrict__ bc_, const float* __restrict__ bo_,
                        uint16_t* __restrict__ ring0, unsigned* __restrict__ flags0,
                        int w)
{
    const int tid  = threadIdx.x;
    const int wave = tid >> 6;
    const int lane = tid & 63;
    const int nloc = lane & 15;
    const int quad = lane >> 4;
    const int col0 = w * 16;
    int budget = SPIN_BUDGET;

    Shared& sh = *(Shared*)smem;
    char* xbufA = smem + SMEM_MISC;           // x(even t) stage, fp32 rows
    char* xbufB = xbufA + 32 * ROWB;          // x(odd t) stage
    load_bias_c(sh, bf_, bi_, bc_, bo_, col0);

    const float* Wg = (wave == 0) ? Wf : (wave == 1) ? Wi : (wave == 2) ? Wc : Wo;
    const float* wrow = Wg + (size_t)(col0 + nloc) * 768 + quad * 8;
    s16x8 B[24];
#pragma unroll
    for (int kt = 0; kt < 24; ++kt) B[kt] = pack8(wrow + kt * 32);

    uint32_t* ring0w = (uint32_t*)ring0;

    // Prologue: stage x(0), x(1); compute xacc(0).
    stage32((const char*)xg,        (size_t)SEQ * 1024, xbufA, lane, wave);
    stage32((const char*)xg + 1024, (size_t)SEQ * 1024, xbufB, lane, wave);
    __builtin_amdgcn_s_waitcnt(0);
    __syncthreads();
    f32x4 xa0 = {0.f, 0.f, 0.f, 0.f};
    f32x4 xa1 = {0.f, 0.f, 0.f, 0.f};
    {
        const char* pxl  = xbufA + nloc * ROWB + quad * 32;
        const char* pxl2 = pxl + 16 * ROWB;
#pragma unroll
        for (int kt = 0; kt < 8; ++kt) {
            xa0 = mfma16(pack8((const float*)(pxl  + kt * 128)), B[kt], xa0);
            xa1 = mfma16(pack8((const float*)(pxl2 + kt * 128)), B[kt], xa1);
        }
    }

#pragma unroll 1
    for (int t = 0; t < SEQ; ++t) {
        // Critical front: poll, then direct-to-register h fragment loads
        // feeding the MFMA chain (no LDS hop, no barrier).
        f32x4 acc0 = xa0;
        f32x4 acc1 = xa1;
        if (t > 0) {
            poll_all32(&flags0[(size_t)(t - 1) * FSTRIDE], budget);
            const char* ph  = (const char*)ring0 + (size_t)(t - 1) * 32768
                            + (size_t)nloc * 1024 + quad * 16;
            const char* ph2 = ph + 16 * 1024;
#pragma unroll
            for (int kt = 0; kt < 16; ++kt) {
                acc0 = mfma16(*(const s16x8*)(ph  + kt * 64), B[8 + kt], acc0);
                acc1 = mfma16(*(const s16x8*)(ph2 + kt * 64), B[8 + kt], acc1);
            }
        }
#pragma unroll
        for (int r = 0; r < 4; ++r) {
            sh.gbuf[wave][quad * 4 + r][nloc]      = acc0[r];
            sh.gbuf[wave][16 + quad * 4 + r][nloc] = acc1[r];
        }
        __syncthreads();
        {
            const int b = tid >> 3, n = (tid & 7) * 2;
            float2 h = gates2(sh, b, n);
            st_u32(ring0w + ((size_t)t * NB + b) * (HID / 2) + (col0 + n) / 2,
                   pack2bf(h.x, h.y));
        }
        __syncthreads();              // all waves' ring stores drained (vmcnt 0)
        if (tid == 0)                 // publish own byte: fire-and-forget
            st_u8((uint8_t*)&flags0[(size_t)t * FSTRIDE] + w, 1);

        // Tail (off the inter-WG chain): precompute xacc(t+1) (x DMA landed —
        // drain barrier above was vmcnt(0)+lgkmcnt(0) for ALL waves);
        // then issue x(t+2) DMA into the freed buffer.
        if (t + 1 < SEQ) {
            const char* xb = ((t + 1) & 1) ? xbufB : xbufA;   // x(t+1)
            const char* pxl  = xb + nloc * ROWB + quad * 32;
            const char* pxl2 = pxl + 16 * ROWB;
            f32x4 a0 = {0.f, 0.f, 0.f, 0.f};
            f32x4 a1 = {0.f, 0.f, 0.f, 0.f};
#pragma unroll
            for (int kt = 0; kt < 8; ++kt) {
                a0 = mfma16(pack8((const float*)(pxl  + kt * 128)), B[kt], a0);
                a1 = mfma16(pack8((const float*)(pxl2 + kt * 128)), B[kt], a1);
            }
            xa0 = a0; xa1 = a1;
        }
        if (t + 2 < SEQ)
            stage32((const char*)xg + (size_t)(t + 2) * 1024, (size_t)SEQ * 1024,
                    (t & 1) ? xbufB : xbufA, lane, wave);      // buf[(t+2)&1]
    }
}

template<bool R1>
__device__ void body_l1(const float* __restrict__ Wf, const float* __restrict__ Wi,
                        const float* __restrict__ Wc, const float* __restrict__ Wo,
                        const float* __restrict__ bf_, const float* __restrict__ bi_,
                        const float* __restrict__ bc_, const float* __restrict__ bo_,
                        float* __restrict__ out,
                        uint16_t* __restrict__ ring0, uint16_t* __restrict__ ring1,
                        unsigned* __restrict__ flags0, unsigned* __restrict__ flags1,
                        int w)
{
    const int tid  = threadIdx.x;
    const int wave = tid >> 6;
    const int lane = tid & 63;
    const int nloc = lane & 15;
    const int quad = lane >> 4;
    const int col0 = w * 16;
    int budget = SPIN_BUDGET;

    Shared& sh = *(Shared*)smem;
    char* hbuf0 = smem + SMEM_MISC;           // h0(t) stage (prefetched in tail)
    load_bias_c(sh, bf_, bi_, bc_, bo_, col0);

    const float* Wg = (wave == 0) ? Wf : (wave == 1) ? Wi : (wave == 2) ? Wc : Wo;
    const float* wrow = Wg + (size_t)(col0 + nloc) * 1024 + quad * 8;
    s16x8 B[32];
#pragma unroll
    for (int kt = 0; kt < 32; ++kt) B[kt] = pack8(wrow + kt * 32);

    uint32_t* ring1w = (uint32_t*)ring1;
    __syncthreads();

    // Prologue: h0(0) (L0 publishes it independently of us).
    poll_all32(&flags0[0], budget);
    stage32((const char*)ring0, 1024, hbuf0, lane, wave);

#pragma unroll 1
    for (int t = 0; t < SEQ; ++t) {
        // h0(t) prefetch DMA landed (mine: waitcnt; all waves: barrier).
        __builtin_amdgcn_s_waitcnt(0);
        __syncthreads();

        // Critical front: poll h1(t-1), ISSUE its register loads first, then
        // run the h0-part LDS MFMAs under the h1 load round trip.
        s16x8 q0[16], q1[16];
        if (t > 0) {
            poll_all32(&flags1[(size_t)(t - 1) * FSTRIDE], budget);
            if (R1) {
                const char* ph  = (const char*)ring1 + (size_t)(t - 1) * 32768
                                + (size_t)nloc * 1024 + quad * 16;
                const char* ph2 = ph + 16 * 1024;
#pragma unroll
                for (int kt = 0; kt < 16; ++kt) {
                    q0[kt] = *(const s16x8*)(ph  + kt * 64);
                    q1[kt] = *(const s16x8*)(ph2 + kt * 64);
                }
            }
        }

        f32x4 acc0 = {0.f, 0.f, 0.f, 0.f};
        f32x4 acc1 = {0.f, 0.f, 0.f, 0.f};
        {   // h0-part from LDS (overlaps h1 loads in flight)
            const char* ph  = hbuf0 + nloc * ROWB + quad * 16;
            const char* ph2 = ph + 16 * ROWB;
#pragma unroll
            for (int kt = 0; kt < 16; ++kt) {
                acc0 = mfma16(*(const s16x8*)(ph  + kt * 64), B[kt], acc0);
                acc1 = mfma16(*(const s16x8*)(ph2 + kt * 64), B[kt], acc1);
            }
        }
        if (t > 0) {   // h1-part
            if (R1) {
#pragma unroll
                for (int kt = 0; kt < 16; ++kt) {
                    acc0 = mfma16(q0[kt], B[16 + kt], acc0);
                    acc1 = mfma16(q1[kt], B[16 + kt], acc1);
                }
            } else {
                const float* po0 = out + ((size_t)nloc * SEQ + (t - 1)) * HID + quad * 8;
                const float* po1 = po0 + (size_t)16 * SEQ * HID;
#pragma unroll
                for (int kt = 0; kt < 16; ++kt) {
                    acc0 = mfma16(pack8(po0 + kt * 32), B[16 + kt], acc0);
                    acc1 = mfma16(pack8(po1 + kt * 32), B[16 + kt], acc1);
                }
            }
        }
#pragma unroll
        for (int r = 0; r < 4; ++r) {
            sh.gbuf[wave][quad * 4 + r][nloc]      = acc0[r];
            sh.gbuf[wave][16 + quad * 4 + r][nloc] = acc1[r];
        }
        __syncthreads();
        {
            const int b = tid >> 3, n = (tid & 7) * 2;
            float2 h = gates2(sh, b, n);
            float* po = &out[((size_t)b * SEQ + t) * HID + col0 + n];
            if (R1) {
                *(float2*)po = h;    // harness-only; flushed at kernel end
                st_u32(ring1w + ((size_t)t * NB + b) * (HID / 2) + (col0 + n) / 2,
                       pack2bf(h.x, h.y));
            } else {
                uint64_t v = (uint64_t)__float_as_uint(h.x)
                           | ((uint64_t)__float_as_uint(h.y) << 32);
                st_u64((uint64_t*)po, v);   // coherent: consumed next step
            }
        }
        __syncthreads();              // ring/out stores drained (vmcnt 0)
        if (tid == 0)
            st_u8((uint8_t*)&flags1[(size_t)t * FSTRIDE] + w, 1);

        // Tail: prefetch h0(t+1) — L0 runs ahead, flag usually already set;
        // the DMA flies across the publish->poll gap of the next iteration.
        if (t + 1 < SEQ) {
            poll_all32(&flags0[(size_t)(t + 1) * FSTRIDE], budget);
            stage32((const char*)ring0 + (size_t)(t + 1) * 32768, 1024,
                    hbuf0, lane, wave);
        }
    }
}

template<bool R1>
__global__ __launch_bounds__(256, 1) void lstm_k(
    const float* __restrict__ x,
    const float* W0f, const float* b0f, const float* W0i, const float* b0i,
    const float* W0c, const float* b0c, const float* W0o, const float* b0o,
    const float* W1f, const float* b1f, const float* W1i, const float* b1i,
    const float* W1c, const float* b1c, const float* W1o, const float* b1o,
    float* out, uint16_t* ring0, uint16_t* ring1,
    unsigned* flags0, unsigned* flags1)
{
    if (blockIdx.x < L0WGS)
        body_l0(x, W0f, W0i, W0c, W0o, b0f, b0i, b0c, b0o,
                ring0, flags0, blockIdx.x);
    else
        body_l1<R1>(W1f, W1i, W1c, W1o, b1f, b1i, b1c, b1o,
                    out, ring0, ring1, flags0, flags1, blockIdx.x - L0WGS);
}

extern "C" void kernel_launch(void* const* d_in, const int* in_sizes, int n_in,
                              void* d_out, int out_size, void* d_ws, size_t ws_size,
                              hipStream_t stream) {
    const float* x   = (const float*)d_in[0];
    const float* W0f = (const float*)d_in[1];  const float* b0f = (const float*)d_in[2];
    const float* W0i = (const float*)d_in[3];  const float* b0i = (const float*)d_in[4];
    const float* W0c = (const float*)d_in[5];  const float* b0c = (const float*)d_in[6];
    const float* W0o = (const float*)d_in[7];  const float* b0o = (const float*)d_in[8];
    const float* W1f = (const float*)d_in[9];  const float* b1f = (const float*)d_in[10];
    const float* W1i = (const float*)d_in[11]; const float* b1i = (const float*)d_in[12];
    const float* W1c = (const float*)d_in[13]; const float* b1c = (const float*)d_in[14];
    const float* W1o = (const float*)d_in[15]; const float* b1o = (const float*)d_in[16];
    float* out = (float*)d_out;

    const size_t flag_bytes = (size_t)SEQ * FSTRIDE * 4;     // 64 KiB each
    const size_t ring_bytes = (size_t)SEQ * NB * HID * 2;    // 32 MiB each
    unsigned* flags0 = (unsigned*)d_ws;
    unsigned* flags1 = flags0 + SEQ * FSTRIDE;
    uint16_t* ring0  = (uint16_t*)((char*)d_ws + 2 * flag_bytes);
    uint16_t* ring1  = (uint16_t*)((char*)d_ws + 2 * flag_bytes + ring_bytes);
    const bool use_r1 = ws_size >= 2 * flag_bytes + 2 * ring_bytes;

    hipFuncSetAttribute((const void*)lstm_k<true>,
                        hipFuncAttributeMaxDynamicSharedMemorySize, SMEM_BYTES);
    hipFuncSetAttribute((const void*)lstm_k<false>,
                        hipFuncAttributeMaxDynamicSharedMemorySize, SMEM_BYTES);

    hipMemsetAsync(d_ws, 0, 2 * flag_bytes, stream);   // zero all flag bytes

    if (use_r1)
        hipLaunchKernelGGL(lstm_k<true>, dim3(NWG), dim3(256), SMEM_BYTES, stream,
            x, W0f, b0f, W0i, b0i, W0c, b0c, W0o, b0o,
            W1f, b1f, W1i, b1i, W1c, b1c, W1o, b1o,
            out, ring0, ring1, flags0, flags1);
    else
        hipLaunchKernelGGL(lstm_k<false>, dim3(NWG), dim3(256), SMEM_BYTES, stream,
            x, W0f, b0f, W0i, b0i, W0c, b0c, W0o, b0o,
            W1f, b1f, W1i, b1i, W1c, b1c, W1o, b1o,
            out, ring0, ring1, flags0, flags1);
}

// Round 9
// 5072.001 us; speedup vs baseline: 1.3396x; 1.3396x over previous
//
#include <hip/hip_runtime.h>
#include <stdint.h>

// Persistent dataflow 2-layer LSTM, MI355X (gfx950).
// Round-12: halve the publish fan-in. r8 (reg-staged h1) spilled to scratch
// (VGPR capped at 192) and regressed 4068->6794; reverted to the r7
// structure. r7 residual theory: per step, 32 producer WGs store a byte
// into the SAME 64B flag line from 32 CUs -> ~32 serialized same-line
// writes at the MALL (~2-3k cy until the LAST byte, which is what the
// consumer's __all exit waits on). Evidence: r0->r3 (RMW->store, same
// fan-in) saved the per-op delta; r6 (fewer pollers, same fan-in) saved 0.
// Now: 512-thread WGs (8 waves), 32 cols/WG -> 16 producers/layer,
// 32 WGs total. Per-wave work unchanged (16 cols of one gate, 32 MFMAs);
// publish fan-in + poll width halve. Sync semantics byte-identical r3/r7.
// VGPR ~192 -> 8 waves/CU legal; __launch_bounds__(512,2) caps alloc.
// HANG-PROOF: per-thread global spin budget; on exhaustion waits no-op.

#define SEQ   1024
#define NB    32
#define HID   512
#define NWG   32                  // total WGs (16 per layer)
#define LWGS  16                  // WGs per layer
#define COLS  32                  // hidden cols per WG
#define FSTRIDE 16                // flag words per step (64B line, 16 bytes used)
#define SPIN_BUDGET (1 << 20)
#define ROWB  1040                // LDS row stride: 1024 data + 16 pad
#define SMEM_MISC 22272           // sizeof(Shared)
#define SMEM_BYTES (SMEM_MISC + 3 * 32 * ROWB)   // 122112 (L0: h + 2x xbuf)

typedef __attribute__((ext_vector_type(8))) short s16x8;
typedef __attribute__((ext_vector_type(4))) float f32x4;

__device__ __forceinline__ uint16_t f2bf(float x) {
    uint32_t u = __float_as_uint(x);
    return (uint16_t)((u + 0x7FFFu + ((u >> 16) & 1u)) >> 16);
}
__device__ __forceinline__ uint32_t pack2bf(float a, float b) {
    return (uint32_t)f2bf(a) | ((uint32_t)f2bf(b) << 16);
}
__device__ __forceinline__ s16x8 pack8(const float* p) {
    float4 a = *(const float4*)p;
    float4 b = *(const float4*)(p + 4);
    s16x8 r;
    r[0] = (short)f2bf(a.x); r[1] = (short)f2bf(a.y);
    r[2] = (short)f2bf(a.z); r[3] = (short)f2bf(a.w);
    r[4] = (short)f2bf(b.x); r[5] = (short)f2bf(b.y);
    r[6] = (short)f2bf(b.z); r[7] = (short)f2bf(b.w);
    return r;
}
__device__ __forceinline__ f32x4 mfma16(s16x8 a, s16x8 b, f32x4 c) {
    return __builtin_amdgcn_mfma_f32_16x16x32_bf16(a, b, c, 0, 0, 0);
}
__device__ __forceinline__ float sigm(float x) { return 1.0f / (1.0f + __expf(-x)); }
__device__ __forceinline__ float tanh_(float x) { return 1.0f - 2.0f / (__expf(2.0f * x) + 1.0f); }

__device__ __forceinline__ void st_u32(uint32_t* p, uint32_t v) {
    __hip_atomic_store(p, v, __ATOMIC_RELAXED, __HIP_MEMORY_SCOPE_AGENT);
}
__device__ __forceinline__ void st_u64(uint64_t* p, uint64_t v) {
    __hip_atomic_store(p, v, __ATOMIC_RELAXED, __HIP_MEMORY_SCOPE_AGENT);
}
__device__ __forceinline__ void st_u8(uint8_t* p, uint8_t v) {
    __hip_atomic_store(p, v, __ATOMIC_RELAXED, __HIP_MEMORY_SCOPE_AGENT);
}
__device__ __forceinline__ unsigned ld_flag(const unsigned* p) {
    return __hip_atomic_load(p, __ATOMIC_RELAXED, __HIP_MEMORY_SCOPE_AGENT);
}
// Wait until all 16 producer bytes in the 64B step slot are 1.
// Lanes 0..3 each load one dword of the line (one coalesced request/wave).
__device__ __forceinline__ void poll16(const unsigned* p, int& budget) {
    const int lane = threadIdx.x & 63;
    for (;;) {
        bool ok = (lane >= 4) || (ld_flag(p + lane) == 0x01010101u);
        if (__all(ok)) break;
        if (--budget < 0) break;          // hang-proof: give up, free-run
        __builtin_amdgcn_s_sleep(1);
    }
    asm volatile("" ::: "memory");        // ring reads stay below the poll
}

// Async global->LDS DMA, 16B/lane. LDS dest = wave-uniform base + lane*16.
__device__ __forceinline__ void dma16(const void* g, void* l) {
    __builtin_amdgcn_global_load_lds(
        (const __attribute__((address_space(1))) unsigned int*)g,
        (__attribute__((address_space(3))) unsigned int*)l, 16, 0, 0);
}
// Stage 32 rows of 1024B into LDS rows of stride ROWB; wave wv does 4 rows.
__device__ __forceinline__ void stage32(const char* gbase, size_t gstride,
                                        char* lbase, int lane, int wv) {
#pragma unroll
    for (int i = 0; i < 4; ++i) {
        const int r = wv * 4 + i;
        dma16(gbase + (size_t)r * gstride + (size_t)lane * 16, lbase + r * ROWB);
    }
}

struct Shared {
    float gbuf[4][NB][34];    // 34-float rows (32 cols + pad)
    float cbuf[NB][34];
    float bbuf[4][COLS];
};

__device__ __forceinline__ void load_bias_c(Shared& sh,
        const float* bf_, const float* bi_, const float* bc_, const float* bo_,
        int colw) {
    const int tid = threadIdx.x;
    if (tid < 32)        sh.bbuf[0][tid]       = bf_[colw + tid];
    else if (tid < 64)   sh.bbuf[1][tid - 32]  = bi_[colw + tid - 32];
    else if (tid < 96)   sh.bbuf[2][tid - 64]  = bc_[colw + tid - 64];
    else if (tid < 128)  sh.bbuf[3][tid - 96]  = bo_[colw + tid - 96];
    float2 z = make_float2(0.f, 0.f);
    ((float2*)sh.cbuf)[tid] = z;                       // 1088 floats = 544 f2
    if (tid < 32) ((float2*)sh.cbuf)[512 + tid] = z;
}

__device__ __forceinline__ float2 gates2(Shared& sh, int b, int n) {
    float2 pf = *(float2*)&sh.gbuf[0][b][n];
    float2 pi = *(float2*)&sh.gbuf[1][b][n];
    float2 pc = *(float2*)&sh.gbuf[2][b][n];
    float2 po = *(float2*)&sh.gbuf[3][b][n];
    float2 h;
    {
        float f = sigm(pf.x + sh.bbuf[0][n]);
        float i = sigm(pi.x + sh.bbuf[1][n]);
        float g = tanh_(pc.x + sh.bbuf[2][n]);
        float o = sigm(po.x + sh.bbuf[3][n]);
        float c = f * sh.cbuf[b][n] + i * g;
        sh.cbuf[b][n] = c;
        h.x = o * tanh_(c);
    }
    {
        float f = sigm(pf.y + sh.bbuf[0][n + 1]);
        float i = sigm(pi.y + sh.bbuf[1][n + 1]);
        float g = tanh_(pc.y + sh.bbuf[2][n + 1]);
        float o = sigm(po.y + sh.bbuf[3][n + 1]);
        float c = f * sh.cbuf[b][n + 1] + i * g;
        sh.cbuf[b][n + 1] = c;
        h.y = o * tanh_(c);
    }
    return h;
}

extern __shared__ char smem[];

__device__ void body_l0(const float* __restrict__ xg,
                        const float* __restrict__ Wf, const float* __restrict__ Wi,
                        const float* __restrict__ Wc, const float* __restrict__ Wo,
                        const float* __restrict__ bf_, const float* __restrict__ bi_,
                        const float* __restrict__ bc_, const float* __restrict__ bo_,
                        uint16_t* __restrict__ ring0, unsigned* __restrict__ flags0,
                        int w)
{
    const int tid  = threadIdx.x;
    const int wave = tid >> 6;           // 0..7
    const int lane = tid & 63;
    const int nloc = lane & 15;
    const int quad = lane >> 4;
    const int gate = wave & 3;
    const int hh   = wave >> 2;          // col half 0/1
    const int colw = w * COLS;           // WG col base
    const int colv = colw + hh * 16;     // wave col base
    int budget = SPIN_BUDGET;

    Shared& sh = *(Shared*)smem;
    char* hbuf  = smem + SMEM_MISC;           // h0(t-1) stage, 32 bf16 rows
    char* xbufA = hbuf + 32 * ROWB;           // x(even t) stage, fp32 rows
    char* xbufB = xbufA + 32 * ROWB;          // x(odd t) stage
    load_bias_c(sh, bf_, bi_, bc_, bo_, colw);

    const float* Wg = (gate == 0) ? Wf : (gate == 1) ? Wi : (gate == 2) ? Wc : Wo;
    const float* wrow = Wg + (size_t)(colv + nloc) * 768 + quad * 8;
    s16x8 B[24];
#pragma unroll
    for (int kt = 0; kt < 24; ++kt) B[kt] = pack8(wrow + kt * 32);

    uint32_t* ring0w = (uint32_t*)ring0;

    // Prologue: stage x(0), x(1); compute xacc(0).
    stage32((const char*)xg,        (size_t)SEQ * 1024, xbufA, lane, wave);
    stage32((const char*)xg + 1024, (size_t)SEQ * 1024, xbufB, lane, wave);
    __builtin_amdgcn_s_waitcnt(0);
    __syncthreads();
    f32x4 xa0 = {0.f, 0.f, 0.f, 0.f};
    f32x4 xa1 = {0.f, 0.f, 0.f, 0.f};
    {
        const char* pxl  = xbufA + nloc * ROWB + quad * 32;
        const char* pxl2 = pxl + 16 * ROWB;
#pragma unroll
        for (int kt = 0; kt < 8; ++kt) {
            xa0 = mfma16(pack8((const float*)(pxl  + kt * 128)), B[kt], xa0);
            xa1 = mfma16(pack8((const float*)(pxl2 + kt * 128)), B[kt], xa1);
        }
    }

#pragma unroll 1
    for (int t = 0; t < SEQ; ++t) {
        // Critical front: own-chain h0(t-1) only (x handled in the tail).
        if (t > 0) {
            poll16(&flags0[(size_t)(t - 1) * FSTRIDE], budget);
            stage32((const char*)ring0 + (size_t)(t - 1) * 32768, 1024,
                    hbuf, lane, wave);
        }
        __builtin_amdgcn_s_waitcnt(0);   // h landed (x prefetches long landed)
        __syncthreads();

        f32x4 acc0 = xa0;                // x-part precomputed last tail
        f32x4 acc1 = xa1;
        if (t > 0) {   // h-part from LDS (bf16)
            const char* ph  = hbuf + nloc * ROWB + quad * 16;
            const char* ph2 = ph + 16 * ROWB;
#pragma unroll
            for (int kt = 0; kt < 16; ++kt) {
                acc0 = mfma16(*(const s16x8*)(ph  + kt * 64), B[8 + kt], acc0);
                acc1 = mfma16(*(const s16x8*)(ph2 + kt * 64), B[8 + kt], acc1);
            }
        }
#pragma unroll
        for (int r = 0; r < 4; ++r) {
            sh.gbuf[gate][quad * 4 + r][hh * 16 + nloc]      = acc0[r];
            sh.gbuf[gate][16 + quad * 4 + r][hh * 16 + nloc] = acc1[r];
        }
        __syncthreads();
        {
            const int b = tid >> 4, n = (tid & 15) * 2;
            float2 h = gates2(sh, b, n);
            st_u32(ring0w + ((size_t)t * NB + b) * (HID / 2) + (colw + n) / 2,
                   pack2bf(h.x, h.y));
        }
        __syncthreads();              // all waves' ring stores drained (vmcnt 0)
        if (tid == 0)                 // publish own byte: fire-and-forget
            st_u8((uint8_t*)&flags0[(size_t)t * FSTRIDE] + w, 1);

        // Tail (off the inter-WG chain): precompute xacc(t+1); issue x(t+2).
        if (t + 1 < SEQ) {
            const char* xb = ((t + 1) & 1) ? xbufB : xbufA;   // x(t+1)
            const char* pxl  = xb + nloc * ROWB + quad * 32;
            const char* pxl2 = pxl + 16 * ROWB;
            f32x4 a0 = {0.f, 0.f, 0.f, 0.f};
            f32x4 a1 = {0.f, 0.f, 0.f, 0.f};
#pragma unroll
            for (int kt = 0; kt < 8; ++kt) {
                a0 = mfma16(pack8((const float*)(pxl  + kt * 128)), B[kt], a0);
                a1 = mfma16(pack8((const float*)(pxl2 + kt * 128)), B[kt], a1);
            }
            xa0 = a0; xa1 = a1;
        }
        if (t + 2 < SEQ)
            stage32((const char*)xg + (size_t)(t + 2) * 1024, (size_t)SEQ * 1024,
                    (t & 1) ? xbufB : xbufA, lane, wave);      // buf[(t+2)&1]
    }
}

template<bool R1>
__device__ void body_l1(const float* __restrict__ Wf, const float* __restrict__ Wi,
                        const float* __restrict__ Wc, const float* __restrict__ Wo,
                        const float* __restrict__ bf_, const float* __restrict__ bi_,
                        const float* __restrict__ bc_, const float* __restrict__ bo_,
                        float* __restrict__ out,
                        uint16_t* __restrict__ ring0, uint16_t* __restrict__ ring1,
                        unsigned* __restrict__ flags0, unsigned* __restrict__ flags1,
                        int w)
{
    const int tid  = threadIdx.x;
    const int wave = tid >> 6;
    const int lane = tid & 63;
    const int nloc = lane & 15;
    const int quad = lane >> 4;
    const int gate = wave & 3;
    const int hh   = wave >> 2;
    const int colw = w * COLS;
    const int colv = colw + hh * 16;
    int budget = SPIN_BUDGET;

    Shared& sh = *(Shared*)smem;
    char* hbuf0 = smem + SMEM_MISC;           // h0(t) stage (prefetched in tail)
    char* hbuf1 = hbuf0 + 32 * ROWB;          // h1(t-1) stage
    load_bias_c(sh, bf_, bi_, bc_, bo_, colw);

    const float* Wg = (gate == 0) ? Wf : (gate == 1) ? Wi : (gate == 2) ? Wc : Wo;
    const float* wrow = Wg + (size_t)(colv + nloc) * 1024 + quad * 8;
    s16x8 B[32];
#pragma unroll
    for (int kt = 0; kt < 32; ++kt) B[kt] = pack8(wrow + kt * 32);

    uint32_t* ring1w = (uint32_t*)ring1;
    __syncthreads();

    // Prologue: h0(0) (L0 publishes it independently of us).
    poll16(&flags0[0], budget);
    stage32((const char*)ring0, 1024, hbuf0, lane, wave);

#pragma unroll 1
    for (int t = 0; t < SEQ; ++t) {
        // Critical front: own-chain h1(t-1) only (h0(t) prefetched in tail).
        if (t > 0) {
            poll16(&flags1[(size_t)(t - 1) * FSTRIDE], budget);
            if (R1)
                stage32((const char*)ring1 + (size_t)(t - 1) * 32768, 1024,
                        hbuf1, lane, wave);
        }
        __builtin_amdgcn_s_waitcnt(0);   // h1 + prefetched h0 landed
        __syncthreads();

        f32x4 acc0 = {0.f, 0.f, 0.f, 0.f};
        f32x4 acc1 = {0.f, 0.f, 0.f, 0.f};
        {   // h0-part (prefetched)
            const char* ph  = hbuf0 + nloc * ROWB + quad * 16;
            const char* ph2 = ph + 16 * ROWB;
#pragma unroll
            for (int kt = 0; kt < 16; ++kt) {
                acc0 = mfma16(*(const s16x8*)(ph  + kt * 64), B[kt], acc0);
                acc1 = mfma16(*(const s16x8*)(ph2 + kt * 64), B[kt], acc1);
            }
        }
        if (t > 0) {   // h1-part
            if (R1) {
                const char* ph  = hbuf1 + nloc * ROWB + quad * 16;
                const char* ph2 = ph + 16 * ROWB;
#pragma unroll
                for (int kt = 0; kt < 16; ++kt) {
                    acc0 = mfma16(*(const s16x8*)(ph  + kt * 64), B[16 + kt], acc0);
                    acc1 = mfma16(*(const s16x8*)(ph2 + kt * 64), B[16 + kt], acc1);
                }
            } else {
                const float* po0 = out + ((size_t)nloc * SEQ + (t - 1)) * HID + quad * 8;
                const float* po1 = po0 + (size_t)16 * SEQ * HID;
#pragma unroll
                for (int kt = 0; kt < 16; ++kt) {
                    acc0 = mfma16(pack8(po0 + kt * 32), B[16 + kt], acc0);
                    acc1 = mfma16(pack8(po1 + kt * 32), B[16 + kt], acc1);
                }
            }
        }
#pragma unroll
        for (int r = 0; r < 4; ++r) {
            sh.gbuf[gate][quad * 4 + r][hh * 16 + nloc]      = acc0[r];
            sh.gbuf[gate][16 + quad * 4 + r][hh * 16 + nloc] = acc1[r];
        }
        __syncthreads();
        {
            const int b = tid >> 4, n = (tid & 15) * 2;
            float2 h = gates2(sh, b, n);
            float* po = &out[((size_t)b * SEQ + t) * HID + colw + n];
            if (R1) {
                *(float2*)po = h;    // harness-only; flushed at kernel end
                st_u32(ring1w + ((size_t)t * NB + b) * (HID / 2) + (colw + n) / 2,
                       pack2bf(h.x, h.y));
            } else {
                uint64_t v = (uint64_t)__float_as_uint(h.x)
                           | ((uint64_t)__float_as_uint(h.y) << 32);
                st_u64((uint64_t*)po, v);   // coherent: consumed next step
            }
        }
        __syncthreads();              // ring/out stores drained (vmcnt 0)
        if (tid == 0)
            st_u8((uint8_t*)&flags1[(size_t)t * FSTRIDE] + w, 1);

        // Tail: prefetch h0(t+1) — L0 runs ahead, flag usually already set;
        // the DMA flies across the publish->poll gap of the next iteration.
        if (t + 1 < SEQ) {
            poll16(&flags0[(size_t)(t + 1) * FSTRIDE], budget);
            stage32((const char*)ring0 + (size_t)(t + 1) * 32768, 1024,
                    hbuf0, lane, wave);
        }
    }
}

template<bool R1>
__global__ __launch_bounds__(512, 2) void lstm_k(
    const float* __restrict__ x,
    const float* W0f, const float* b0f, const float* W0i, const float* b0i,
    const float* W0c, const float* b0c, const float* W0o, const float* b0o,
    const float* W1f, const float* b1f, const float* W1i, const float* b1i,
    const float* W1c, const float* b1c, const float* W1o, const float* b1o,
    float* out, uint16_t* ring0, uint16_t* ring1,
    unsigned* flags0, unsigned* flags1)
{
    if (blockIdx.x < LWGS)
        body_l0(x, W0f, W0i, W0c, W0o, b0f, b0i, b0c, b0o,
                ring0, flags0, blockIdx.x);
    else
        body_l1<R1>(W1f, W1i, W1c, W1o, b1f, b1i, b1c, b1o,
                    out, ring0, ring1, flags0, flags1, blockIdx.x - LWGS);
}

extern "C" void kernel_launch(void* const* d_in, const int* in_sizes, int n_in,
                              void* d_out, int out_size, void* d_ws, size_t ws_size,
                              hipStream_t stream) {
    const float* x   = (const float*)d_in[0];
    const float* W0f = (const float*)d_in[1];  const float* b0f = (const float*)d_in[2];
    const float* W0i = (const float*)d_in[3];  const float* b0i = (const float*)d_in[4];
    const float* W0c = (const float*)d_in[5];  const float* b0c = (const float*)d_in[6];
    const float* W0o = (const float*)d_in[7];  const float* b0o = (const float*)d_in[8];
    const float* W1f = (const float*)d_in[9];  const float* b1f = (const float*)d_in[10];
    const float* W1i = (const float*)d_in[11]; const float* b1i = (const float*)d_in[12];
    const float* W1c = (const float*)d_in[13]; const float* b1c = (const float*)d_in[14];
    const float* W1o = (const float*)d_in[15]; const float* b1o = (const float*)d_in[16];
    float* out = (float*)d_out;

    const size_t flag_bytes = (size_t)SEQ * FSTRIDE * 4;     // 64 KiB each
    const size_t ring_bytes = (size_t)SEQ * NB * HID * 2;    // 32 MiB each
    unsigned* flags0 = (unsigned*)d_ws;
    unsigned* flags1 = flags0 + SEQ * FSTRIDE;
    uint16_t* ring0  = (uint16_t*)((char*)d_ws + 2 * flag_bytes);
    uint16_t* ring1  = (uint16_t*)((char*)d_ws + 2 * flag_bytes + ring_bytes);
    const bool use_r1 = ws_size >= 2 * flag_bytes + 2 * ring_bytes;

    hipFuncSetAttribute((const void*)lstm_k<true>,
                        hipFuncAttributeMaxDynamicSharedMemorySize, SMEM_BYTES);
    hipFuncSetAttribute((const void*)lstm_k<false>,
                        hipFuncAttributeMaxDynamicSharedMemorySize, SMEM_BYTES);

    hipMemsetAsync(d_ws, 0, 2 * flag_bytes, stream);   // zero all flag bytes

    if (use_r1)
        hipLaunchKernelGGL(lstm_k<true>, dim3(NWG), dim3(512), SMEM_BYTES, stream,
            x, W0f, b0f, W0i, b0i, W0c, b0c, W0o, b0o,
            W1f, b1f, W1i, b1i, W1c, b1c, W1o, b1o,
            out, ring0, ring1, flags0, flags1);
    else
        hipLaunchKernelGGL(lstm_k<false>, dim3(NWG), dim3(512), SMEM_BYTES, stream,
            x, W0f, b0f, W0i, b0i, W0c, b0c, W0o, b0o,
            W1f, b1f, W1i, b1i, W1c, b1c, W1o, b1o,
            out, ring0, ring1, flags0, flags1);
}

// Round 10
// 4039.728 us; speedup vs baseline: 1.6819x; 1.2555x over previous
//
#include <hip/hip_runtime.h>
#include <stdint.h>

// Persistent dataflow 2-layer LSTM, MI355X (gfx950).
// 64 WGs x 256 thr: WGs 0..31 = layer0 (16 h-cols each), 32..63 = layer1.
// Round-13: base = verified r7 (4068us). r8 (reg-staged h1) and r9 (512-thr
// WGs) both regressed via VGPR-budget spills; reverted. This round: ONE
// change, in body_l1 only — the h0-part MFMAs (which depend only on the
// tail-prefetched h0(t), NOT on flags1) move BEFORE the flags1 poll, so the
// flags1 publish->visibility window (~600-950cy) hides under ~500cy of
// MFMA work instead of sitting serially on L1's critical chain.
// Summation order bitwise unchanged (h0-part into zero-init acc, then
// h1-part). Sync semantics byte-identical r3/r7. L0 untouched.
// HANG-PROOF: per-thread global spin budget; on exhaustion waits no-op.

#define SEQ   1024
#define NB    32
#define HID   512
#define NWG   64
#define L0WGS 32
#define FSTRIDE 16                // flag words per step (64B line, 32 bytes used)
#define SPIN_BUDGET (1 << 20)
#define ROWB  1040                // LDS row stride: 1024 data + 16 pad
#define SMEM_MISC 11776           // sizeof(Shared) with 18-float rows
#define SMEM_BYTES (SMEM_MISC + 3 * 32 * ROWB)   // 111616 (L0: h + 2x xbuf)

typedef __attribute__((ext_vector_type(8))) short s16x8;
typedef __attribute__((ext_vector_type(4))) float f32x4;

__device__ __forceinline__ uint16_t f2bf(float x) {
    uint32_t u = __float_as_uint(x);
    return (uint16_t)((u + 0x7FFFu + ((u >> 16) & 1u)) >> 16);
}
__device__ __forceinline__ uint32_t pack2bf(float a, float b) {
    return (uint32_t)f2bf(a) | ((uint32_t)f2bf(b) << 16);
}
__device__ __forceinline__ s16x8 pack8(const float* p) {
    float4 a = *(const float4*)p;
    float4 b = *(const float4*)(p + 4);
    s16x8 r;
    r[0] = (short)f2bf(a.x); r[1] = (short)f2bf(a.y);
    r[2] = (short)f2bf(a.z); r[3] = (short)f2bf(a.w);
    r[4] = (short)f2bf(b.x); r[5] = (short)f2bf(b.y);
    r[6] = (short)f2bf(b.z); r[7] = (short)f2bf(b.w);
    return r;
}
__device__ __forceinline__ f32x4 mfma16(s16x8 a, s16x8 b, f32x4 c) {
    return __builtin_amdgcn_mfma_f32_16x16x32_bf16(a, b, c, 0, 0, 0);
}
__device__ __forceinline__ float sigm(float x) { return 1.0f / (1.0f + __expf(-x)); }
__device__ __forceinline__ float tanh_(float x) { return 1.0f - 2.0f / (__expf(2.0f * x) + 1.0f); }

__device__ __forceinline__ void st_u32(uint32_t* p, uint32_t v) {
    __hip_atomic_store(p, v, __ATOMIC_RELAXED, __HIP_MEMORY_SCOPE_AGENT);
}
__device__ __forceinline__ void st_u64(uint64_t* p, uint64_t v) {
    __hip_atomic_store(p, v, __ATOMIC_RELAXED, __HIP_MEMORY_SCOPE_AGENT);
}
__device__ __forceinline__ void st_u8(uint8_t* p, uint8_t v) {
    __hip_atomic_store(p, v, __ATOMIC_RELAXED, __HIP_MEMORY_SCOPE_AGENT);
}
__device__ __forceinline__ unsigned ld_flag(const unsigned* p) {
    return __hip_atomic_load(p, __ATOMIC_RELAXED, __HIP_MEMORY_SCOPE_AGENT);
}
// Wait until all 32 producer bytes in the 64B step slot are 1.
// Lanes 0..7 each load one dword of the line (one coalesced request/wave).
__device__ __forceinline__ void poll_all32(const unsigned* p, int& budget) {
    const int lane = threadIdx.x & 63;
    for (;;) {
        bool ok = (lane >= 8) || (ld_flag(p + lane) == 0x01010101u);
        if (__all(ok)) break;
        if (--budget < 0) break;          // hang-proof: give up, free-run
        __builtin_amdgcn_s_sleep(1);
    }
    asm volatile("" ::: "memory");        // ring reads stay below the poll
}

// Async global->LDS DMA, 16B/lane. LDS dest = wave-uniform base + lane*16.
__device__ __forceinline__ void dma16(const void* g, void* l) {
    __builtin_amdgcn_global_load_lds(
        (const __attribute__((address_space(1))) unsigned int*)g,
        (__attribute__((address_space(3))) unsigned int*)l, 16, 0, 0);
}
// Stage 32 rows of 1024B into LDS rows of stride ROWB; wave wv does 8 rows.
__device__ __forceinline__ void stage32(const char* gbase, size_t gstride,
                                        char* lbase, int lane, int wv) {
#pragma unroll
    for (int i = 0; i < 8; ++i) {
        const int r = wv * 8 + i;
        dma16(gbase + (size_t)r * gstride + (size_t)lane * 16, lbase + r * ROWB);
    }
}

struct Shared {
    float gbuf[4][NB][18];    // 18-float rows
    float cbuf[NB][18];
    float bbuf[4][16];
};

__device__ __forceinline__ void load_bias_c(Shared& sh,
        const float* bf_, const float* bi_, const float* bc_, const float* bo_,
        int col0) {
    const int tid = threadIdx.x;
    if (tid < 16)       sh.bbuf[0][tid]      = bf_[col0 + tid];
    else if (tid < 32)  sh.bbuf[1][tid - 16] = bi_[col0 + tid - 16];
    else if (tid < 48)  sh.bbuf[2][tid - 32] = bc_[col0 + tid - 32];
    else if (tid < 64)  sh.bbuf[3][tid - 48] = bo_[col0 + tid - 48];
    float2 z = make_float2(0.f, 0.f);
    ((float2*)sh.cbuf)[tid] = z;                       // 576 floats = 288 f2
    if (tid < 32) ((float2*)sh.cbuf)[256 + tid] = z;
}

__device__ __forceinline__ float2 gates2(Shared& sh, int b, int n) {
    float2 pf = *(float2*)&sh.gbuf[0][b][n];
    float2 pi = *(float2*)&sh.gbuf[1][b][n];
    float2 pc = *(float2*)&sh.gbuf[2][b][n];
    float2 po = *(float2*)&sh.gbuf[3][b][n];
    float2 h;
    {
        float f = sigm(pf.x + sh.bbuf[0][n]);
        float i = sigm(pi.x + sh.bbuf[1][n]);
        float g = tanh_(pc.x + sh.bbuf[2][n]);
        float o = sigm(po.x + sh.bbuf[3][n]);
        float c = f * sh.cbuf[b][n] + i * g;
        sh.cbuf[b][n] = c;
        h.x = o * tanh_(c);
    }
    {
        float f = sigm(pf.y + sh.bbuf[0][n + 1]);
        float i = sigm(pi.y + sh.bbuf[1][n + 1]);
        float g = tanh_(pc.y + sh.bbuf[2][n + 1]);
        float o = sigm(po.y + sh.bbuf[3][n + 1]);
        float c = f * sh.cbuf[b][n + 1] + i * g;
        sh.cbuf[b][n + 1] = c;
        h.y = o * tanh_(c);
    }
    return h;
}

extern __shared__ char smem[];

__device__ void body_l0(const float* __restrict__ xg,
                        const float* __restrict__ Wf, const float* __restrict__ Wi,
                        const float* __restrict__ Wc, const float* __restrict__ Wo,
                        const float* __restrict__ bf_, const float* __restrict__ bi_,
                        const float* __restrict__ bc_, const float* __restrict__ bo_,
                        uint16_t* __restrict__ ring0, unsigned* __restrict__ flags0,
                        int w)
{
    const int tid  = threadIdx.x;
    const int wave = tid >> 6;
    const int lane = tid & 63;
    const int nloc = lane & 15;
    const int quad = lane >> 4;
    const int col0 = w * 16;
    int budget = SPIN_BUDGET;

    Shared& sh = *(Shared*)smem;
    char* hbuf  = smem + SMEM_MISC;           // h0(t-1) stage, 32 bf16 rows
    char* xbufA = hbuf + 32 * ROWB;           // x(even t) stage, fp32 rows
    char* xbufB = xbufA + 32 * ROWB;          // x(odd t) stage
    load_bias_c(sh, bf_, bi_, bc_, bo_, col0);

    const float* Wg = (wave == 0) ? Wf : (wave == 1) ? Wi : (wave == 2) ? Wc : Wo;
    const float* wrow = Wg + (size_t)(col0 + nloc) * 768 + quad * 8;
    s16x8 B[24];
#pragma unroll
    for (int kt = 0; kt < 24; ++kt) B[kt] = pack8(wrow + kt * 32);

    uint32_t* ring0w = (uint32_t*)ring0;

    // Prologue: stage x(0), x(1); compute xacc(0).
    stage32((const char*)xg,        (size_t)SEQ * 1024, xbufA, lane, wave);
    stage32((const char*)xg + 1024, (size_t)SEQ * 1024, xbufB, lane, wave);
    __builtin_amdgcn_s_waitcnt(0);
    __syncthreads();
    f32x4 xa0 = {0.f, 0.f, 0.f, 0.f};
    f32x4 xa1 = {0.f, 0.f, 0.f, 0.f};
    {
        const char* pxl  = xbufA + nloc * ROWB + quad * 32;
        const char* pxl2 = pxl + 16 * ROWB;
#pragma unroll
        for (int kt = 0; kt < 8; ++kt) {
            xa0 = mfma16(pack8((const float*)(pxl  + kt * 128)), B[kt], xa0);
            xa1 = mfma16(pack8((const float*)(pxl2 + kt * 128)), B[kt], xa1);
        }
    }

#pragma unroll 1
    for (int t = 0; t < SEQ; ++t) {
        // Critical front: own-chain h0(t-1) only (x handled in the tail).
        if (t > 0) {
            poll_all32(&flags0[(size_t)(t - 1) * FSTRIDE], budget);
            stage32((const char*)ring0 + (size_t)(t - 1) * 32768, 1024,
                    hbuf, lane, wave);
        }
        __builtin_amdgcn_s_waitcnt(0);   // h landed (x prefetches long landed)
        __syncthreads();

        f32x4 acc0 = xa0;                // x-part precomputed last tail
        f32x4 acc1 = xa1;
        if (t > 0) {   // h-part from LDS (bf16)
            const char* ph  = hbuf + nloc * ROWB + quad * 16;
            const char* ph2 = ph + 16 * ROWB;
#pragma unroll
            for (int kt = 0; kt < 16; ++kt) {
                acc0 = mfma16(*(const s16x8*)(ph  + kt * 64), B[8 + kt], acc0);
                acc1 = mfma16(*(const s16x8*)(ph2 + kt * 64), B[8 + kt], acc1);
            }
        }
#pragma unroll
        for (int r = 0; r < 4; ++r) {
            sh.gbuf[wave][quad * 4 + r][nloc]      = acc0[r];
            sh.gbuf[wave][16 + quad * 4 + r][nloc] = acc1[r];
        }
        __syncthreads();
        {
            const int b = tid >> 3, n = (tid & 7) * 2;
            float2 h = gates2(sh, b, n);
            st_u32(ring0w + ((size_t)t * NB + b) * (HID / 2) + (col0 + n) / 2,
                   pack2bf(h.x, h.y));
        }
        __syncthreads();              // all waves' ring stores drained (vmcnt 0)
        if (tid == 0)                 // publish own byte: fire-and-forget
            st_u8((uint8_t*)&flags0[(size_t)t * FSTRIDE] + w, 1);

        // Tail (off the inter-WG chain): precompute xacc(t+1); issue x(t+2).
        if (t + 1 < SEQ) {
            const char* xb = ((t + 1) & 1) ? xbufB : xbufA;   // x(t+1)
            const char* pxl  = xb + nloc * ROWB + quad * 32;
            const char* pxl2 = pxl + 16 * ROWB;
            f32x4 a0 = {0.f, 0.f, 0.f, 0.f};
            f32x4 a1 = {0.f, 0.f, 0.f, 0.f};
#pragma unroll
            for (int kt = 0; kt < 8; ++kt) {
                a0 = mfma16(pack8((const float*)(pxl  + kt * 128)), B[kt], a0);
                a1 = mfma16(pack8((const float*)(pxl2 + kt * 128)), B[kt], a1);
            }
            xa0 = a0; xa1 = a1;
        }
        if (t + 2 < SEQ)
            stage32((const char*)xg + (size_t)(t + 2) * 1024, (size_t)SEQ * 1024,
                    (t & 1) ? xbufB : xbufA, lane, wave);      // buf[(t+2)&1]
    }
}

template<bool R1>
__device__ void body_l1(const float* __restrict__ Wf, const float* __restrict__ Wi,
                        const float* __restrict__ Wc, const float* __restrict__ Wo,
                        const float* __restrict__ bf_, const float* __restrict__ bi_,
                        const float* __restrict__ bc_, const float* __restrict__ bo_,
                        float* __restrict__ out,
                        uint16_t* __restrict__ ring0, uint16_t* __restrict__ ring1,
                        unsigned* __restrict__ flags0, unsigned* __restrict__ flags1,
                        int w)
{
    const int tid  = threadIdx.x;
    const int wave = tid >> 6;
    const int lane = tid & 63;
    const int nloc = lane & 15;
    const int quad = lane >> 4;
    const int col0 = w * 16;
    int budget = SPIN_BUDGET;

    Shared& sh = *(Shared*)smem;
    char* hbuf0 = smem + SMEM_MISC;           // h0(t) stage (prefetched in tail)
    char* hbuf1 = hbuf0 + 32 * ROWB;          // h1(t-1) stage
    load_bias_c(sh, bf_, bi_, bc_, bo_, col0);

    const float* Wg = (wave == 0) ? Wf : (wave == 1) ? Wi : (wave == 2) ? Wc : Wo;
    const float* wrow = Wg + (size_t)(col0 + nloc) * 1024 + quad * 8;
    s16x8 B[32];
#pragma unroll
    for (int kt = 0; kt < 32; ++kt) B[kt] = pack8(wrow + kt * 32);

    uint32_t* ring1w = (uint32_t*)ring1;
    __syncthreads();

    // Prologue: h0(0) (L0 publishes it independently of us).
    poll_all32(&flags0[0], budget);
    stage32((const char*)ring0, 1024, hbuf0, lane, wave);

#pragma unroll 1
    for (int t = 0; t < SEQ; ++t) {
        // h0(t) prefetch DMA landed (all waves).
        __builtin_amdgcn_s_waitcnt(0);
        __syncthreads();

        // h0-part FIRST (depends only on prefetched h0(t)) — this ~500cy of
        // MFMA work hides the flags1(t-1) publish->visibility latency that
        // the poll below would otherwise expose serially.
        f32x4 acc0 = {0.f, 0.f, 0.f, 0.f};
        f32x4 acc1 = {0.f, 0.f, 0.f, 0.f};
        {
            const char* ph  = hbuf0 + nloc * ROWB + quad * 16;
            const char* ph2 = ph + 16 * ROWB;
#pragma unroll
            for (int kt = 0; kt < 16; ++kt) {
                acc0 = mfma16(*(const s16x8*)(ph  + kt * 64), B[kt], acc0);
                acc1 = mfma16(*(const s16x8*)(ph2 + kt * 64), B[kt], acc1);
            }
        }

        // Own-chain h1(t-1): poll (likely already visible), stage, compute.
        if (t > 0) {
            poll_all32(&flags1[(size_t)(t - 1) * FSTRIDE], budget);
            if (R1) {
                stage32((const char*)ring1 + (size_t)(t - 1) * 32768, 1024,
                        hbuf1, lane, wave);
                __builtin_amdgcn_s_waitcnt(0);
                __syncthreads();
                const char* ph  = hbuf1 + nloc * ROWB + quad * 16;
                const char* ph2 = ph + 16 * ROWB;
#pragma unroll
                for (int kt = 0; kt < 16; ++kt) {
                    acc0 = mfma16(*(const s16x8*)(ph  + kt * 64), B[16 + kt], acc0);
                    acc1 = mfma16(*(const s16x8*)(ph2 + kt * 64), B[16 + kt], acc1);
                }
            } else {
                const float* po0 = out + ((size_t)nloc * SEQ + (t - 1)) * HID + quad * 8;
                const float* po1 = po0 + (size_t)16 * SEQ * HID;
#pragma unroll
                for (int kt = 0; kt < 16; ++kt) {
                    acc0 = mfma16(pack8(po0 + kt * 32), B[16 + kt], acc0);
                    acc1 = mfma16(pack8(po1 + kt * 32), B[16 + kt], acc1);
                }
            }
        }
#pragma unroll
        for (int r = 0; r < 4; ++r) {
            sh.gbuf[wave][quad * 4 + r][nloc]      = acc0[r];
            sh.gbuf[wave][16 + quad * 4 + r][nloc] = acc1[r];
        }
        __syncthreads();
        {
            const int b = tid >> 3, n = (tid & 7) * 2;
            float2 h = gates2(sh, b, n);
            float* po = &out[((size_t)b * SEQ + t) * HID + col0 + n];
            if (R1) {
                *(float2*)po = h;    // harness-only; flushed at kernel end
                st_u32(ring1w + ((size_t)t * NB + b) * (HID / 2) + (col0 + n) / 2,
                       pack2bf(h.x, h.y));
            } else {
                uint64_t v = (uint64_t)__float_as_uint(h.x)
                           | ((uint64_t)__float_as_uint(h.y) << 32);
                st_u64((uint64_t*)po, v);   // coherent: consumed next step
            }
        }
        __syncthreads();              // ring/out stores drained (vmcnt 0)
        if (tid == 0)
            st_u8((uint8_t*)&flags1[(size_t)t * FSTRIDE] + w, 1);

        // Tail: prefetch h0(t+1) — L0 runs ahead, flag usually already set;
        // the DMA flies across the publish->poll gap of the next iteration.
        if (t + 1 < SEQ) {
            poll_all32(&flags0[(size_t)(t + 1) * FSTRIDE], budget);
            stage32((const char*)ring0 + (size_t)(t + 1) * 32768, 1024,
                    hbuf0, lane, wave);
        }
    }
}

template<bool R1>
__global__ __launch_bounds__(256, 1) void lstm_k(
    const float* __restrict__ x,
    const float* W0f, const float* b0f, const float* W0i, const float* b0i,
    const float* W0c, const float* b0c, const float* W0o, const float* b0o,
    const float* W1f, const float* b1f, const float* W1i, const float* b1i,
    const float* W1c, const float* b1c, const float* W1o, const float* b1o,
    float* out, uint16_t* ring0, uint16_t* ring1,
    unsigned* flags0, unsigned* flags1)
{
    if (blockIdx.x < L0WGS)
        body_l0(x, W0f, W0i, W0c, W0o, b0f, b0i, b0c, b0o,
                ring0, flags0, blockIdx.x);
    else
        body_l1<R1>(W1f, W1i, W1c, W1o, b1f, b1i, b1c, b1o,
                    out, ring0, ring1, flags0, flags1, blockIdx.x - L0WGS);
}

extern "C" void kernel_launch(void* const* d_in, const int* in_sizes, int n_in,
                              void* d_out, int out_size, void* d_ws, size_t ws_size,
                              hipStream_t stream) {
    const float* x   = (const float*)d_in[0];
    const float* W0f = (const float*)d_in[1];  const float* b0f = (const float*)d_in[2];
    const float* W0i = (const float*)d_in[3];  const float* b0i = (const float*)d_in[4];
    const float* W0c = (const float*)d_in[5];  const float* b0c = (const float*)d_in[6];
    const float* W0o = (const float*)d_in[7];  const float* b0o = (const float*)d_in[8];
    const float* W1f = (const float*)d_in[9];  const float* b1f = (const float*)d_in[10];
    const float* W1i = (const float*)d_in[11]; const float* b1i = (const float*)d_in[12];
    const float* W1c = (const float*)d_in[13]; const float* b1c = (const float*)d_in[14];
    const float* W1o = (const float*)d_in[15]; const float* b1o = (const float*)d_in[16];
    float* out = (float*)d_out;

    const size_t flag_bytes = (size_t)SEQ * FSTRIDE * 4;     // 64 KiB each
    const size_t ring_bytes = (size_t)SEQ * NB * HID * 2;    // 32 MiB each
    unsigned* flags0 = (unsigned*)d_ws;
    unsigned* flags1 = flags0 + SEQ * FSTRIDE;
    uint16_t* ring0  = (uint16_t*)((char*)d_ws + 2 * flag_bytes);
    uint16_t* ring1  = (uint16_t*)((char*)d_ws + 2 * flag_bytes + ring_bytes);
    const bool use_r1 = ws_size >= 2 * flag_bytes + 2 * ring_bytes;

    hipFuncSetAttribute((const void*)lstm_k<true>,
                        hipFuncAttributeMaxDynamicSharedMemorySize, SMEM_BYTES);
    hipFuncSetAttribute((const void*)lstm_k<false>,
                        hipFuncAttributeMaxDynamicSharedMemorySize, SMEM_BYTES);

    hipMemsetAsync(d_ws, 0, 2 * flag_bytes, stream);   // zero all flag bytes

    if (use_r1)
        hipLaunchKernelGGL(lstm_k<true>, dim3(NWG), dim3(256), SMEM_BYTES, stream,
            x, W0f, b0f, W0i, b0i, W0c, b0c, W0o, b0o,
            W1f, b1f, W1i, b1i, W1c, b1c, W1o, b1o,
            out, ring0, ring1, flags0, flags1);
    else
        hipLaunchKernelGGL(lstm_k<false>, dim3(NWG), dim3(256), SMEM_BYTES, stream,
            x, W0f, b0f, W0i, b0i, W0c, b0c, W0o, b0o,
            W1f, b1f, W1i, b1i, W1c, b1c, W1o, b1o,
            out, ring0, ring1, flags0, flags1);
}

// Round 11
// 4003.251 us; speedup vs baseline: 1.6972x; 1.0091x over previous
//
#include <hip/hip_runtime.h>
#include <stdint.h>

// Persistent dataflow 2-layer LSTM, MI355X (gfx950).
// 64 WGs x 256 thr: WGs 0..31 = layer0 (16 h-cols each), 32..63 = layer1.
// Round-14: base = r10 (verified 4040us). ONE change: remove s_sleep(1)
// from the poll loops (busy-spin). Cycle accounting at 2.4GHz puts the
// structural chain at 1.3-1.9us/step but we measure 3.85us/step — a ~2x
// multiplier consistent with SCLK throttling: ~3-5% busy + s_sleep in
// every poll invites CU clock-gating / low DPM state (~1.2-1.3GHz), which
// stretches EVERY serial segment. Busy-spin keeps waves nominally active.
// Sync semantics otherwise byte-identical to the verified r3/r6/r10 scheme
// (per-step 64B line, byte flags, == dword compare, drain-then-publish).
// Poll storm contention was disproven in r6 (4x fewer pollers = flat).
// HANG-PROOF: per-thread global spin budget; on exhaustion waits no-op.

#define SEQ   1024
#define NB    32
#define HID   512
#define NWG   64
#define L0WGS 32
#define FSTRIDE 16                // flag words per step (64B line, 32 bytes used)
#define SPIN_BUDGET (1 << 20)
#define ROWB  1040                // LDS row stride: 1024 data + 16 pad
#define SMEM_MISC 11776           // sizeof(Shared) with 18-float rows
#define SMEM_BYTES (SMEM_MISC + 3 * 32 * ROWB)   // 111616 (L0: h + 2x xbuf)

typedef __attribute__((ext_vector_type(8))) short s16x8;
typedef __attribute__((ext_vector_type(4))) float f32x4;

__device__ __forceinline__ uint16_t f2bf(float x) {
    uint32_t u = __float_as_uint(x);
    return (uint16_t)((u + 0x7FFFu + ((u >> 16) & 1u)) >> 16);
}
__device__ __forceinline__ uint32_t pack2bf(float a, float b) {
    return (uint32_t)f2bf(a) | ((uint32_t)f2bf(b) << 16);
}
__device__ __forceinline__ s16x8 pack8(const float* p) {
    float4 a = *(const float4*)p;
    float4 b = *(const float4*)(p + 4);
    s16x8 r;
    r[0] = (short)f2bf(a.x); r[1] = (short)f2bf(a.y);
    r[2] = (short)f2bf(a.z); r[3] = (short)f2bf(a.w);
    r[4] = (short)f2bf(b.x); r[5] = (short)f2bf(b.y);
    r[6] = (short)f2bf(b.z); r[7] = (short)f2bf(b.w);
    return r;
}
__device__ __forceinline__ f32x4 mfma16(s16x8 a, s16x8 b, f32x4 c) {
    return __builtin_amdgcn_mfma_f32_16x16x32_bf16(a, b, c, 0, 0, 0);
}
__device__ __forceinline__ float sigm(float x) { return 1.0f / (1.0f + __expf(-x)); }
__device__ __forceinline__ float tanh_(float x) { return 1.0f - 2.0f / (__expf(2.0f * x) + 1.0f); }

__device__ __forceinline__ void st_u32(uint32_t* p, uint32_t v) {
    __hip_atomic_store(p, v, __ATOMIC_RELAXED, __HIP_MEMORY_SCOPE_AGENT);
}
__device__ __forceinline__ void st_u64(uint64_t* p, uint64_t v) {
    __hip_atomic_store(p, v, __ATOMIC_RELAXED, __HIP_MEMORY_SCOPE_AGENT);
}
__device__ __forceinline__ void st_u8(uint8_t* p, uint8_t v) {
    __hip_atomic_store(p, v, __ATOMIC_RELAXED, __HIP_MEMORY_SCOPE_AGENT);
}
__device__ __forceinline__ unsigned ld_flag(const unsigned* p) {
    return __hip_atomic_load(p, __ATOMIC_RELAXED, __HIP_MEMORY_SCOPE_AGENT);
}
// Wait until all 32 producer bytes in the 64B step slot are 1.
// Lanes 0..7 each load one dword of the line (one coalesced request/wave).
// Busy-spin (no s_sleep): keeps the CU out of clock-gated idle states.
__device__ __forceinline__ void poll_all32(const unsigned* p, int& budget) {
    const int lane = threadIdx.x & 63;
    for (;;) {
        bool ok = (lane >= 8) || (ld_flag(p + lane) == 0x01010101u);
        if (__all(ok)) break;
        if (--budget < 0) break;          // hang-proof: give up, free-run
    }
    asm volatile("" ::: "memory");        // ring reads stay below the poll
}

// Async global->LDS DMA, 16B/lane. LDS dest = wave-uniform base + lane*16.
__device__ __forceinline__ void dma16(const void* g, void* l) {
    __builtin_amdgcn_global_load_lds(
        (const __attribute__((address_space(1))) unsigned int*)g,
        (__attribute__((address_space(3))) unsigned int*)l, 16, 0, 0);
}
// Stage 32 rows of 1024B into LDS rows of stride ROWB; wave wv does 8 rows.
__device__ __forceinline__ void stage32(const char* gbase, size_t gstride,
                                        char* lbase, int lane, int wv) {
#pragma unroll
    for (int i = 0; i < 8; ++i) {
        const int r = wv * 8 + i;
        dma16(gbase + (size_t)r * gstride + (size_t)lane * 16, lbase + r * ROWB);
    }
}

struct Shared {
    float gbuf[4][NB][18];    // 18-float rows
    float cbuf[NB][18];
    float bbuf[4][16];
};

__device__ __forceinline__ void load_bias_c(Shared& sh,
        const float* bf_, const float* bi_, const float* bc_, const float* bo_,
        int col0) {
    const int tid = threadIdx.x;
    if (tid < 16)       sh.bbuf[0][tid]      = bf_[col0 + tid];
    else if (tid < 32)  sh.bbuf[1][tid - 16] = bi_[col0 + tid - 16];
    else if (tid < 48)  sh.bbuf[2][tid - 32] = bc_[col0 + tid - 32];
    else if (tid < 64)  sh.bbuf[3][tid - 48] = bo_[col0 + tid - 48];
    float2 z = make_float2(0.f, 0.f);
    ((float2*)sh.cbuf)[tid] = z;                       // 576 floats = 288 f2
    if (tid < 32) ((float2*)sh.cbuf)[256 + tid] = z;
}

__device__ __forceinline__ float2 gates2(Shared& sh, int b, int n) {
    float2 pf = *(float2*)&sh.gbuf[0][b][n];
    float2 pi = *(float2*)&sh.gbuf[1][b][n];
    float2 pc = *(float2*)&sh.gbuf[2][b][n];
    float2 po = *(float2*)&sh.gbuf[3][b][n];
    float2 h;
    {
        float f = sigm(pf.x + sh.bbuf[0][n]);
        float i = sigm(pi.x + sh.bbuf[1][n]);
        float g = tanh_(pc.x + sh.bbuf[2][n]);
        float o = sigm(po.x + sh.bbuf[3][n]);
        float c = f * sh.cbuf[b][n] + i * g;
        sh.cbuf[b][n] = c;
        h.x = o * tanh_(c);
    }
    {
        float f = sigm(pf.y + sh.bbuf[0][n + 1]);
        float i = sigm(pi.y + sh.bbuf[1][n + 1]);
        float g = tanh_(pc.y + sh.bbuf[2][n + 1]);
        float o = sigm(po.y + sh.bbuf[3][n + 1]);
        float c = f * sh.cbuf[b][n + 1] + i * g;
        sh.cbuf[b][n + 1] = c;
        h.y = o * tanh_(c);
    }
    return h;
}

extern __shared__ char smem[];

__device__ void body_l0(const float* __restrict__ xg,
                        const float* __restrict__ Wf, const float* __restrict__ Wi,
                        const float* __restrict__ Wc, const float* __restrict__ Wo,
                        const float* __restrict__ bf_, const float* __restrict__ bi_,
                        const float* __restrict__ bc_, const float* __restrict__ bo_,
                        uint16_t* __restrict__ ring0, unsigned* __restrict__ flags0,
                        int w)
{
    const int tid  = threadIdx.x;
    const int wave = tid >> 6;
    const int lane = tid & 63;
    const int nloc = lane & 15;
    const int quad = lane >> 4;
    const int col0 = w * 16;
    int budget = SPIN_BUDGET;

    Shared& sh = *(Shared*)smem;
    char* hbuf  = smem + SMEM_MISC;           // h0(t-1) stage, 32 bf16 rows
    char* xbufA = hbuf + 32 * ROWB;           // x(even t) stage, fp32 rows
    char* xbufB = xbufA + 32 * ROWB;          // x(odd t) stage
    load_bias_c(sh, bf_, bi_, bc_, bo_, col0);

    const float* Wg = (wave == 0) ? Wf : (wave == 1) ? Wi : (wave == 2) ? Wc : Wo;
    const float* wrow = Wg + (size_t)(col0 + nloc) * 768 + quad * 8;
    s16x8 B[24];
#pragma unroll
    for (int kt = 0; kt < 24; ++kt) B[kt] = pack8(wrow + kt * 32);

    uint32_t* ring0w = (uint32_t*)ring0;

    // Prologue: stage x(0), x(1); compute xacc(0).
    stage32((const char*)xg,        (size_t)SEQ * 1024, xbufA, lane, wave);
    stage32((const char*)xg + 1024, (size_t)SEQ * 1024, xbufB, lane, wave);
    __builtin_amdgcn_s_waitcnt(0);
    __syncthreads();
    f32x4 xa0 = {0.f, 0.f, 0.f, 0.f};
    f32x4 xa1 = {0.f, 0.f, 0.f, 0.f};
    {
        const char* pxl  = xbufA + nloc * ROWB + quad * 32;
        const char* pxl2 = pxl + 16 * ROWB;
#pragma unroll
        for (int kt = 0; kt < 8; ++kt) {
            xa0 = mfma16(pack8((const float*)(pxl  + kt * 128)), B[kt], xa0);
            xa1 = mfma16(pack8((const float*)(pxl2 + kt * 128)), B[kt], xa1);
        }
    }

#pragma unroll 1
    for (int t = 0; t < SEQ; ++t) {
        // Critical front: own-chain h0(t-1) only (x handled in the tail).
        if (t > 0) {
            poll_all32(&flags0[(size_t)(t - 1) * FSTRIDE], budget);
            stage32((const char*)ring0 + (size_t)(t - 1) * 32768, 1024,
                    hbuf, lane, wave);
        }
        __builtin_amdgcn_s_waitcnt(0);   // h landed (x prefetches long landed)
        __syncthreads();

        f32x4 acc0 = xa0;                // x-part precomputed last tail
        f32x4 acc1 = xa1;
        if (t > 0) {   // h-part from LDS (bf16)
            const char* ph  = hbuf + nloc * ROWB + quad * 16;
            const char* ph2 = ph + 16 * ROWB;
#pragma unroll
            for (int kt = 0; kt < 16; ++kt) {
                acc0 = mfma16(*(const s16x8*)(ph  + kt * 64), B[8 + kt], acc0);
                acc1 = mfma16(*(const s16x8*)(ph2 + kt * 64), B[8 + kt], acc1);
            }
        }
#pragma unroll
        for (int r = 0; r < 4; ++r) {
            sh.gbuf[wave][quad * 4 + r][nloc]      = acc0[r];
            sh.gbuf[wave][16 + quad * 4 + r][nloc] = acc1[r];
        }
        __syncthreads();
        {
            const int b = tid >> 3, n = (tid & 7) * 2;
            float2 h = gates2(sh, b, n);
            st_u32(ring0w + ((size_t)t * NB + b) * (HID / 2) + (col0 + n) / 2,
                   pack2bf(h.x, h.y));
        }
        __syncthreads();              // all waves' ring stores drained (vmcnt 0)
        if (tid == 0)                 // publish own byte: fire-and-forget
            st_u8((uint8_t*)&flags0[(size_t)t * FSTRIDE] + w, 1);

        // Tail (off the inter-WG chain): precompute xacc(t+1); issue x(t+2).
        if (t + 1 < SEQ) {
            const char* xb = ((t + 1) & 1) ? xbufB : xbufA;   // x(t+1)
            const char* pxl  = xb + nloc * ROWB + quad * 32;
            const char* pxl2 = pxl + 16 * ROWB;
            f32x4 a0 = {0.f, 0.f, 0.f, 0.f};
            f32x4 a1 = {0.f, 0.f, 0.f, 0.f};
#pragma unroll
            for (int kt = 0; kt < 8; ++kt) {
                a0 = mfma16(pack8((const float*)(pxl  + kt * 128)), B[kt], a0);
                a1 = mfma16(pack8((const float*)(pxl2 + kt * 128)), B[kt], a1);
            }
            xa0 = a0; xa1 = a1;
        }
        if (t + 2 < SEQ)
            stage32((const char*)xg + (size_t)(t + 2) * 1024, (size_t)SEQ * 1024,
                    (t & 1) ? xbufB : xbufA, lane, wave);      // buf[(t+2)&1]
    }
}

template<bool R1>
__device__ void body_l1(const float* __restrict__ Wf, const float* __restrict__ Wi,
                        const float* __restrict__ Wc, const float* __restrict__ Wo,
                        const float* __restrict__ bf_, const float* __restrict__ bi_,
                        const float* __restrict__ bc_, const float* __restrict__ bo_,
                        float* __restrict__ out,
                        uint16_t* __restrict__ ring0, uint16_t* __restrict__ ring1,
                        unsigned* __restrict__ flags0, unsigned* __restrict__ flags1,
                        int w)
{
    const int tid  = threadIdx.x;
    const int wave = tid >> 6;
    const int lane = tid & 63;
    const int nloc = lane & 15;
    const int quad = lane >> 4;
    const int col0 = w * 16;
    int budget = SPIN_BUDGET;

    Shared& sh = *(Shared*)smem;
    char* hbuf0 = smem + SMEM_MISC;           // h0(t) stage (prefetched in tail)
    char* hbuf1 = hbuf0 + 32 * ROWB;          // h1(t-1) stage
    load_bias_c(sh, bf_, bi_, bc_, bo_, col0);

    const float* Wg = (wave == 0) ? Wf : (wave == 1) ? Wi : (wave == 2) ? Wc : Wo;
    const float* wrow = Wg + (size_t)(col0 + nloc) * 1024 + quad * 8;
    s16x8 B[32];
#pragma unroll
    for (int kt = 0; kt < 32; ++kt) B[kt] = pack8(wrow + kt * 32);

    uint32_t* ring1w = (uint32_t*)ring1;
    __syncthreads();

    // Prologue: h0(0) (L0 publishes it independently of us).
    poll_all32(&flags0[0], budget);
    stage32((const char*)ring0, 1024, hbuf0, lane, wave);

#pragma unroll 1
    for (int t = 0; t < SEQ; ++t) {
        // h0(t) prefetch DMA landed (all waves).
        __builtin_amdgcn_s_waitcnt(0);
        __syncthreads();

        // h0-part FIRST (depends only on prefetched h0(t)) — hides the
        // flags1(t-1) publish->visibility latency under ~500cy of MFMAs.
        f32x4 acc0 = {0.f, 0.f, 0.f, 0.f};
        f32x4 acc1 = {0.f, 0.f, 0.f, 0.f};
        {
            const char* ph  = hbuf0 + nloc * ROWB + quad * 16;
            const char* ph2 = ph + 16 * ROWB;
#pragma unroll
            for (int kt = 0; kt < 16; ++kt) {
                acc0 = mfma16(*(const s16x8*)(ph  + kt * 64), B[kt], acc0);
                acc1 = mfma16(*(const s16x8*)(ph2 + kt * 64), B[kt], acc1);
            }
        }

        // Own-chain h1(t-1): poll (likely already visible), stage, compute.
        if (t > 0) {
            poll_all32(&flags1[(size_t)(t - 1) * FSTRIDE], budget);
            if (R1) {
                stage32((const char*)ring1 + (size_t)(t - 1) * 32768, 1024,
                        hbuf1, lane, wave);
                __builtin_amdgcn_s_waitcnt(0);
                __syncthreads();
                const char* ph  = hbuf1 + nloc * ROWB + quad * 16;
                const char* ph2 = ph + 16 * ROWB;
#pragma unroll
                for (int kt = 0; kt < 16; ++kt) {
                    acc0 = mfma16(*(const s16x8*)(ph  + kt * 64), B[16 + kt], acc0);
                    acc1 = mfma16(*(const s16x8*)(ph2 + kt * 64), B[16 + kt], acc1);
                }
            } else {
                const float* po0 = out + ((size_t)nloc * SEQ + (t - 1)) * HID + quad * 8;
                const float* po1 = po0 + (size_t)16 * SEQ * HID;
#pragma unroll
                for (int kt = 0; kt < 16; ++kt) {
                    acc0 = mfma16(pack8(po0 + kt * 32), B[16 + kt], acc0);
                    acc1 = mfma16(pack8(po1 + kt * 32), B[16 + kt], acc1);
                }
            }
        }
#pragma unroll
        for (int r = 0; r < 4; ++r) {
            sh.gbuf[wave][quad * 4 + r][nloc]      = acc0[r];
            sh.gbuf[wave][16 + quad * 4 + r][nloc] = acc1[r];
        }
        __syncthreads();
        {
            const int b = tid >> 3, n = (tid & 7) * 2;
            float2 h = gates2(sh, b, n);
            float* po = &out[((size_t)b * SEQ + t) * HID + col0 + n];
            if (R1) {
                *(float2*)po = h;    // harness-only; flushed at kernel end
                st_u32(ring1w + ((size_t)t * NB + b) * (HID / 2) + (col0 + n) / 2,
                       pack2bf(h.x, h.y));
            } else {
                uint64_t v = (uint64_t)__float_as_uint(h.x)
                           | ((uint64_t)__float_as_uint(h.y) << 32);
                st_u64((uint64_t*)po, v);   // coherent: consumed next step
            }
        }
        __syncthreads();              // ring/out stores drained (vmcnt 0)
        if (tid == 0)
            st_u8((uint8_t*)&flags1[(size_t)t * FSTRIDE] + w, 1);

        // Tail: prefetch h0(t+1) — L0 runs ahead, flag usually already set;
        // the DMA flies across the publish->poll gap of the next iteration.
        if (t + 1 < SEQ) {
            poll_all32(&flags0[(size_t)(t + 1) * FSTRIDE], budget);
            stage32((const char*)ring0 + (size_t)(t + 1) * 32768, 1024,
                    hbuf0, lane, wave);
        }
    }
}

template<bool R1>
__global__ __launch_bounds__(256, 1) void lstm_k(
    const float* __restrict__ x,
    const float* W0f, const float* b0f, const float* W0i, const float* b0i,
    const float* W0c, const float* b0c, const float* W0o, const float* b0o,
    const float* W1f, const float* b1f, const float* W1i, const float* b1i,
    const float* W1c, const float* b1c, const float* W1o, const float* b1o,
    float* out, uint16_t* ring0, uint16_t* ring1,
    unsigned* flags0, unsigned* flags1)
{
    if (blockIdx.x < L0WGS)
        body_l0(x, W0f, W0i, W0c, W0o, b0f, b0i, b0c, b0o,
                ring0, flags0, blockIdx.x);
    else
        body_l1<R1>(W1f, W1i, W1c, W1o, b1f, b1i, b1c, b1o,
                    out, ring0, ring1, flags0, flags1, blockIdx.x - L0WGS);
}

extern "C" void kernel_launch(void* const* d_in, const int* in_sizes, int n_in,
                              void* d_out, int out_size, void* d_ws, size_t ws_size,
                              hipStream_t stream) {
    const float* x   = (const float*)d_in[0];
    const float* W0f = (const float*)d_in[1];  const float* b0f = (const float*)d_in[2];
    const float* W0i = (const float*)d_in[3];  const float* b0i = (const float*)d_in[4];
    const float* W0c = (const float*)d_in[5];  const float* b0c = (const float*)d_in[6];
    const float* W0o = (const float*)d_in[7];  const float* b0o = (const float*)d_in[8];
    const float* W1f = (const float*)d_in[9];  const float* b1f = (const float*)d_in[10];
    const float* W1i = (const float*)d_in[11]; const float* b1i = (const float*)d_in[12];
    const float* W1c = (const float*)d_in[13]; const float* b1c = (const float*)d_in[14];
    const float* W1o = (const float*)d_in[15]; const float* b1o = (const float*)d_in[16];
    float* out = (float*)d_out;

    const size_t flag_bytes = (size_t)SEQ * FSTRIDE * 4;     // 64 KiB each
    const size_t ring_bytes = (size_t)SEQ * NB * HID * 2;    // 32 MiB each
    unsigned* flags0 = (unsigned*)d_ws;
    unsigned* flags1 = flags0 + SEQ * FSTRIDE;
    uint16_t* ring0  = (uint16_t*)((char*)d_ws + 2 * flag_bytes);
    uint16_t* ring1  = (uint16_t*)((char*)d_ws + 2 * flag_bytes + ring_bytes);
    const bool use_r1 = ws_size >= 2 * flag_bytes + 2 * ring_bytes;

    hipFuncSetAttribute((const void*)lstm_k<true>,
                        hipFuncAttributeMaxDynamicSharedMemorySize, SMEM_BYTES);
    hipFuncSetAttribute((const void*)lstm_k<false>,
                        hipFuncAttributeMaxDynamicSharedMemorySize, SMEM_BYTES);

    hipMemsetAsync(d_ws, 0, 2 * flag_bytes, stream);   // zero all flag bytes

    if (use_r1)
        hipLaunchKernelGGL(lstm_k<true>, dim3(NWG), dim3(256), SMEM_BYTES, stream,
            x, W0f, b0f, W0i, b0i, W0c, b0c, W0o, b0o,
            W1f, b1f, W1i, b1i, W1c, b1c, W1o, b1o,
            out, ring0, ring1, flags0, flags1);
    else
        hipLaunchKernelGGL(lstm_k<false>, dim3(NWG), dim3(256), SMEM_BYTES, stream,
            x, W0f, b0f, W0i, b0i, W0c, b0c, W0o, b0o,
            W1f, b1f, W1i, b1i, W1c, b1c, W1o, b1o,
            out, ring0, ring1, flags0, flags1);
}

// Round 12
// 3799.796 us; speedup vs baseline: 1.7881x; 1.0535x over previous
//
#include <hip/hip_runtime.h>
#include <stdint.h>

// Persistent dataflow 2-layer LSTM, MI355X (gfx950).
// 64 WGs x 256 thr: WGs 0..31 = layer0 (16 h-cols each), 32..63 = layer1.
// Round-15: base = r11 (verified 4003us). ONE change: VALU HEATER in the
// poll loop. Structural cycle accounting (vis + detect-RT + stage-RT +
// compute + drain ~= 3300-4700 cy) matches the measured 3.94us/step at
// ~1.2GHz, not 2.4GHz — eleven structural levers each moved exactly their
// modeled cycle count or nothing, consistent with a correct model at HALF
// the assumed clock. r11's busy-spin didn't raise aggregate utilization
// (~3% busy either way), so DPM had no reason to raise SCLK. Now every
// waiting wave (the dominant residency state) runs a dense FMA chain
// between flag checks -> chip-wide VALU activity ~30-50% -> governor holds
// high SCLK. Heater writes only dead registers (asm sink); detect
// granularity worsens ~130cy/check; all sync/data semantics byte-identical
// to r10/r11. If flat, clock theory is dead and the residual is genuine
// cross-XCD RT cost.
// HANG-PROOF: per-thread global spin budget; on exhaustion waits no-op.

#define SEQ   1024
#define NB    32
#define HID   512
#define NWG   64
#define L0WGS 32
#define FSTRIDE 16                // flag words per step (64B line, 32 bytes used)
#define SPIN_BUDGET (1 << 20)
#define ROWB  1040                // LDS row stride: 1024 data + 16 pad
#define SMEM_MISC 11776           // sizeof(Shared) with 18-float rows
#define SMEM_BYTES (SMEM_MISC + 3 * 32 * ROWB)   // 111616 (L0: h + 2x xbuf)

typedef __attribute__((ext_vector_type(8))) short s16x8;
typedef __attribute__((ext_vector_type(4))) float f32x4;

__device__ __forceinline__ uint16_t f2bf(float x) {
    uint32_t u = __float_as_uint(x);
    return (uint16_t)((u + 0x7FFFu + ((u >> 16) & 1u)) >> 16);
}
__device__ __forceinline__ uint32_t pack2bf(float a, float b) {
    return (uint32_t)f2bf(a) | ((uint32_t)f2bf(b) << 16);
}
__device__ __forceinline__ s16x8 pack8(const float* p) {
    float4 a = *(const float4*)p;
    float4 b = *(const float4*)(p + 4);
    s16x8 r;
    r[0] = (short)f2bf(a.x); r[1] = (short)f2bf(a.y);
    r[2] = (short)f2bf(a.z); r[3] = (short)f2bf(a.w);
    r[4] = (short)f2bf(b.x); r[5] = (short)f2bf(b.y);
    r[6] = (short)f2bf(b.z); r[7] = (short)f2bf(b.w);
    return r;
}
__device__ __forceinline__ f32x4 mfma16(s16x8 a, s16x8 b, f32x4 c) {
    return __builtin_amdgcn_mfma_f32_16x16x32_bf16(a, b, c, 0, 0, 0);
}
__device__ __forceinline__ float sigm(float x) { return 1.0f / (1.0f + __expf(-x)); }
__device__ __forceinline__ float tanh_(float x) { return 1.0f - 2.0f / (__expf(2.0f * x) + 1.0f); }

__device__ __forceinline__ void st_u32(uint32_t* p, uint32_t v) {
    __hip_atomic_store(p, v, __ATOMIC_RELAXED, __HIP_MEMORY_SCOPE_AGENT);
}
__device__ __forceinline__ void st_u64(uint64_t* p, uint64_t v) {
    __hip_atomic_store(p, v, __ATOMIC_RELAXED, __HIP_MEMORY_SCOPE_AGENT);
}
__device__ __forceinline__ void st_u8(uint8_t* p, uint8_t v) {
    __hip_atomic_store(p, v, __ATOMIC_RELAXED, __HIP_MEMORY_SCOPE_AGENT);
}
__device__ __forceinline__ unsigned ld_flag(const unsigned* p) {
    return __hip_atomic_load(p, __ATOMIC_RELAXED, __HIP_MEMORY_SCOPE_AGENT);
}
// Wait until all 32 producer bytes in the 64B step slot are 1.
// Lanes 0..7 each load one dword of the line (one coalesced request/wave).
// HEATER: dense FMA chain between checks keeps chip-wide VALU activity
// high so the DPM governor holds high SCLK (dead registers, asm sink).
__device__ __forceinline__ void poll_all32(const unsigned* p, int& budget) {
    const int lane = threadIdx.x & 63;
    float h0 = 1.0f, h1 = 1.0f, h2 = 1.0f, h3 = 1.0f;
    for (;;) {
        bool ok = (lane >= 8) || (ld_flag(p + lane) == 0x01010101u);
        if (__all(ok)) break;
        if (--budget < 0) break;          // hang-proof: give up, free-run
#pragma unroll
        for (int i = 0; i < 16; ++i) {    // 4 indep chains x 16 deep
            h0 = __builtin_fmaf(h0, 1.0000001f, 1e-7f);
            h1 = __builtin_fmaf(h1, 0.9999999f, 1e-7f);
            h2 = __builtin_fmaf(h2, 1.0000002f, 1e-7f);
            h3 = __builtin_fmaf(h3, 0.9999998f, 1e-7f);
        }
        asm volatile("" :: "v"(h0), "v"(h1), "v"(h2), "v"(h3));
    }
    asm volatile("" ::: "memory");        // ring reads stay below the poll
}

// Async global->LDS DMA, 16B/lane. LDS dest = wave-uniform base + lane*16.
__device__ __forceinline__ void dma16(const void* g, void* l) {
    __builtin_amdgcn_global_load_lds(
        (const __attribute__((address_space(1))) unsigned int*)g,
        (__attribute__((address_space(3))) unsigned int*)l, 16, 0, 0);
}
// Stage 32 rows of 1024B into LDS rows of stride ROWB; wave wv does 8 rows.
__device__ __forceinline__ void stage32(const char* gbase, size_t gstride,
                                        char* lbase, int lane, int wv) {
#pragma unroll
    for (int i = 0; i < 8; ++i) {
        const int r = wv * 8 + i;
        dma16(gbase + (size_t)r * gstride + (size_t)lane * 16, lbase + r * ROWB);
    }
}

struct Shared {
    float gbuf[4][NB][18];    // 18-float rows
    float cbuf[NB][18];
    float bbuf[4][16];
};

__device__ __forceinline__ void load_bias_c(Shared& sh,
        const float* bf_, const float* bi_, const float* bc_, const float* bo_,
        int col0) {
    const int tid = threadIdx.x;
    if (tid < 16)       sh.bbuf[0][tid]      = bf_[col0 + tid];
    else if (tid < 32)  sh.bbuf[1][tid - 16] = bi_[col0 + tid - 16];
    else if (tid < 48)  sh.bbuf[2][tid - 32] = bc_[col0 + tid - 32];
    else if (tid < 64)  sh.bbuf[3][tid - 48] = bo_[col0 + tid - 48];
    float2 z = make_float2(0.f, 0.f);
    ((float2*)sh.cbuf)[tid] = z;                       // 576 floats = 288 f2
    if (tid < 32) ((float2*)sh.cbuf)[256 + tid] = z;
}

__device__ __forceinline__ float2 gates2(Shared& sh, int b, int n) {
    float2 pf = *(float2*)&sh.gbuf[0][b][n];
    float2 pi = *(float2*)&sh.gbuf[1][b][n];
    float2 pc = *(float2*)&sh.gbuf[2][b][n];
    float2 po = *(float2*)&sh.gbuf[3][b][n];
    float2 h;
    {
        float f = sigm(pf.x + sh.bbuf[0][n]);
        float i = sigm(pi.x + sh.bbuf[1][n]);
        float g = tanh_(pc.x + sh.bbuf[2][n]);
        float o = sigm(po.x + sh.bbuf[3][n]);
        float c = f * sh.cbuf[b][n] + i * g;
        sh.cbuf[b][n] = c;
        h.x = o * tanh_(c);
    }
    {
        float f = sigm(pf.y + sh.bbuf[0][n + 1]);
        float i = sigm(pi.y + sh.bbuf[1][n + 1]);
        float g = tanh_(pc.y + sh.bbuf[2][n + 1]);
        float o = sigm(po.y + sh.bbuf[3][n + 1]);
        float c = f * sh.cbuf[b][n + 1] + i * g;
        sh.cbuf[b][n + 1] = c;
        h.y = o * tanh_(c);
    }
    return h;
}

extern __shared__ char smem[];

__device__ void body_l0(const float* __restrict__ xg,
                        const float* __restrict__ Wf, const float* __restrict__ Wi,
                        const float* __restrict__ Wc, const float* __restrict__ Wo,
                        const float* __restrict__ bf_, const float* __restrict__ bi_,
                        const float* __restrict__ bc_, const float* __restrict__ bo_,
                        uint16_t* __restrict__ ring0, unsigned* __restrict__ flags0,
                        int w)
{
    const int tid  = threadIdx.x;
    const int wave = tid >> 6;
    const int lane = tid & 63;
    const int nloc = lane & 15;
    const int quad = lane >> 4;
    const int col0 = w * 16;
    int budget = SPIN_BUDGET;

    Shared& sh = *(Shared*)smem;
    char* hbuf  = smem + SMEM_MISC;           // h0(t-1) stage, 32 bf16 rows
    char* xbufA = hbuf + 32 * ROWB;           // x(even t) stage, fp32 rows
    char* xbufB = xbufA + 32 * ROWB;          // x(odd t) stage
    load_bias_c(sh, bf_, bi_, bc_, bo_, col0);

    const float* Wg = (wave == 0) ? Wf : (wave == 1) ? Wi : (wave == 2) ? Wc : Wo;
    const float* wrow = Wg + (size_t)(col0 + nloc) * 768 + quad * 8;
    s16x8 B[24];
#pragma unroll
    for (int kt = 0; kt < 24; ++kt) B[kt] = pack8(wrow + kt * 32);

    uint32_t* ring0w = (uint32_t*)ring0;

    // Prologue: stage x(0), x(1); compute xacc(0).
    stage32((const char*)xg,        (size_t)SEQ * 1024, xbufA, lane, wave);
    stage32((const char*)xg + 1024, (size_t)SEQ * 1024, xbufB, lane, wave);
    __builtin_amdgcn_s_waitcnt(0);
    __syncthreads();
    f32x4 xa0 = {0.f, 0.f, 0.f, 0.f};
    f32x4 xa1 = {0.f, 0.f, 0.f, 0.f};
    {
        const char* pxl  = xbufA + nloc * ROWB + quad * 32;
        const char* pxl2 = pxl + 16 * ROWB;
#pragma unroll
        for (int kt = 0; kt < 8; ++kt) {
            xa0 = mfma16(pack8((const float*)(pxl  + kt * 128)), B[kt], xa0);
            xa1 = mfma16(pack8((const float*)(pxl2 + kt * 128)), B[kt], xa1);
        }
    }

#pragma unroll 1
    for (int t = 0; t < SEQ; ++t) {
        // Critical front: own-chain h0(t-1) only (x handled in the tail).
        if (t > 0) {
            poll_all32(&flags0[(size_t)(t - 1) * FSTRIDE], budget);
            stage32((const char*)ring0 + (size_t)(t - 1) * 32768, 1024,
                    hbuf, lane, wave);
        }
        __builtin_amdgcn_s_waitcnt(0);   // h landed (x prefetches long landed)
        __syncthreads();

        f32x4 acc0 = xa0;                // x-part precomputed last tail
        f32x4 acc1 = xa1;
        if (t > 0) {   // h-part from LDS (bf16)
            const char* ph  = hbuf + nloc * ROWB + quad * 16;
            const char* ph2 = ph + 16 * ROWB;
#pragma unroll
            for (int kt = 0; kt < 16; ++kt) {
                acc0 = mfma16(*(const s16x8*)(ph  + kt * 64), B[8 + kt], acc0);
                acc1 = mfma16(*(const s16x8*)(ph2 + kt * 64), B[8 + kt], acc1);
            }
        }
#pragma unroll
        for (int r = 0; r < 4; ++r) {
            sh.gbuf[wave][quad * 4 + r][nloc]      = acc0[r];
            sh.gbuf[wave][16 + quad * 4 + r][nloc] = acc1[r];
        }
        __syncthreads();
        {
            const int b = tid >> 3, n = (tid & 7) * 2;
            float2 h = gates2(sh, b, n);
            st_u32(ring0w + ((size_t)t * NB + b) * (HID / 2) + (col0 + n) / 2,
                   pack2bf(h.x, h.y));
        }
        __syncthreads();              // all waves' ring stores drained (vmcnt 0)
        if (tid == 0)                 // publish own byte: fire-and-forget
            st_u8((uint8_t*)&flags0[(size_t)t * FSTRIDE] + w, 1);

        // Tail (off the inter-WG chain): precompute xacc(t+1); issue x(t+2).
        if (t + 1 < SEQ) {
            const char* xb = ((t + 1) & 1) ? xbufB : xbufA;   // x(t+1)
            const char* pxl  = xb + nloc * ROWB + quad * 32;
            const char* pxl2 = pxl + 16 * ROWB;
            f32x4 a0 = {0.f, 0.f, 0.f, 0.f};
            f32x4 a1 = {0.f, 0.f, 0.f, 0.f};
#pragma unroll
            for (int kt = 0; kt < 8; ++kt) {
                a0 = mfma16(pack8((const float*)(pxl  + kt * 128)), B[kt], a0);
                a1 = mfma16(pack8((const float*)(pxl2 + kt * 128)), B[kt], a1);
            }
            xa0 = a0; xa1 = a1;
        }
        if (t + 2 < SEQ)
            stage32((const char*)xg + (size_t)(t + 2) * 1024, (size_t)SEQ * 1024,
                    (t & 1) ? xbufB : xbufA, lane, wave);      // buf[(t+2)&1]
    }
}

template<bool R1>
__device__ void body_l1(const float* __restrict__ Wf, const float* __restrict__ Wi,
                        const float* __restrict__ Wc, const float* __restrict__ Wo,
                        const float* __restrict__ bf_, const float* __restrict__ bi_,
                        const float* __restrict__ bc_, const float* __restrict__ bo_,
                        float* __restrict__ out,
                        uint16_t* __restrict__ ring0, uint16_t* __restrict__ ring1,
                        unsigned* __restrict__ flags0, unsigned* __restrict__ flags1,
                        int w)
{
    const int tid  = threadIdx.x;
    const int wave = tid >> 6;
    const int lane = tid & 63;
    const int nloc = lane & 15;
    const int quad = lane >> 4;
    const int col0 = w * 16;
    int budget = SPIN_BUDGET;

    Shared& sh = *(Shared*)smem;
    char* hbuf0 = smem + SMEM_MISC;           // h0(t) stage (prefetched in tail)
    char* hbuf1 = hbuf0 + 32 * ROWB;          // h1(t-1) stage
    load_bias_c(sh, bf_, bi_, bc_, bo_, col0);

    const float* Wg = (wave == 0) ? Wf : (wave == 1) ? Wi : (wave == 2) ? Wc : Wo;
    const float* wrow = Wg + (size_t)(col0 + nloc) * 1024 + quad * 8;
    s16x8 B[32];
#pragma unroll
    for (int kt = 0; kt < 32; ++kt) B[kt] = pack8(wrow + kt * 32);

    uint32_t* ring1w = (uint32_t*)ring1;
    __syncthreads();

    // Prologue: h0(0) (L0 publishes it independently of us).
    poll_all32(&flags0[0], budget);
    stage32((const char*)ring0, 1024, hbuf0, lane, wave);

#pragma unroll 1
    for (int t = 0; t < SEQ; ++t) {
        // h0(t) prefetch DMA landed (all waves).
        __builtin_amdgcn_s_waitcnt(0);
        __syncthreads();

        // h0-part FIRST (depends only on prefetched h0(t)) — hides the
        // flags1(t-1) publish->visibility latency under ~500cy of MFMAs.
        f32x4 acc0 = {0.f, 0.f, 0.f, 0.f};
        f32x4 acc1 = {0.f, 0.f, 0.f, 0.f};
        {
            const char* ph  = hbuf0 + nloc * ROWB + quad * 16;
            const char* ph2 = ph + 16 * ROWB;
#pragma unroll
            for (int kt = 0; kt < 16; ++kt) {
                acc0 = mfma16(*(const s16x8*)(ph  + kt * 64), B[kt], acc0);
                acc1 = mfma16(*(const s16x8*)(ph2 + kt * 64), B[kt], acc1);
            }
        }

        // Own-chain h1(t-1): poll (likely already visible), stage, compute.
        if (t > 0) {
            poll_all32(&flags1[(size_t)(t - 1) * FSTRIDE], budget);
            if (R1) {
                stage32((const char*)ring1 + (size_t)(t - 1) * 32768, 1024,
                        hbuf1, lane, wave);
                __builtin_amdgcn_s_waitcnt(0);
                __syncthreads();
                const char* ph  = hbuf1 + nloc * ROWB + quad * 16;
                const char* ph2 = ph + 16 * ROWB;
#pragma unroll
                for (int kt = 0; kt < 16; ++kt) {
                    acc0 = mfma16(*(const s16x8*)(ph  + kt * 64), B[16 + kt], acc0);
                    acc1 = mfma16(*(const s16x8*)(ph2 + kt * 64), B[16 + kt], acc1);
                }
            } else {
                const float* po0 = out + ((size_t)nloc * SEQ + (t - 1)) * HID + quad * 8;
                const float* po1 = po0 + (size_t)16 * SEQ * HID;
#pragma unroll
                for (int kt = 0; kt < 16; ++kt) {
                    acc0 = mfma16(pack8(po0 + kt * 32), B[16 + kt], acc0);
                    acc1 = mfma16(pack8(po1 + kt * 32), B[16 + kt], acc1);
                }
            }
        }
#pragma unroll
        for (int r = 0; r < 4; ++r) {
            sh.gbuf[wave][quad * 4 + r][nloc]      = acc0[r];
            sh.gbuf[wave][16 + quad * 4 + r][nloc] = acc1[r];
        }
        __syncthreads();
        {
            const int b = tid >> 3, n = (tid & 7) * 2;
            float2 h = gates2(sh, b, n);
            float* po = &out[((size_t)b * SEQ + t) * HID + col0 + n];
            if (R1) {
                *(float2*)po = h;    // harness-only; flushed at kernel end
                st_u32(ring1w + ((size_t)t * NB + b) * (HID / 2) + (col0 + n) / 2,
                       pack2bf(h.x, h.y));
            } else {
                uint64_t v = (uint64_t)__float_as_uint(h.x)
                           | ((uint64_t)__float_as_uint(h.y) << 32);
                st_u64((uint64_t*)po, v);   // coherent: consumed next step
            }
        }
        __syncthreads();              // ring/out stores drained (vmcnt 0)
        if (tid == 0)
            st_u8((uint8_t*)&flags1[(size_t)t * FSTRIDE] + w, 1);

        // Tail: prefetch h0(t+1) — L0 runs ahead, flag usually already set;
        // the DMA flies across the publish->poll gap of the next iteration.
        if (t + 1 < SEQ) {
            poll_all32(&flags0[(size_t)(t + 1) * FSTRIDE], budget);
            stage32((const char*)ring0 + (size_t)(t + 1) * 32768, 1024,
                    hbuf0, lane, wave);
        }
    }
}

template<bool R1>
__global__ __launch_bounds__(256, 1) void lstm_k(
    const float* __restrict__ x,
    const float* W0f, const float* b0f, const float* W0i, const float* b0i,
    const float* W0c, const float* b0c, const float* W0o, const float* b0o,
    const float* W1f, const float* b1f, const float* W1i, const float* b1i,
    const float* W1c, const float* b1c, const float* W1o, const float* b1o,
    float* out, uint16_t* ring0, uint16_t* ring1,
    unsigned* flags0, unsigned* flags1)
{
    if (blockIdx.x < L0WGS)
        body_l0(x, W0f, W0i, W0c, W0o, b0f, b0i, b0c, b0o,
                ring0, flags0, blockIdx.x);
    else
        body_l1<R1>(W1f, W1i, W1c, W1o, b1f, b1i, b1c, b1o,
                    out, ring0, ring1, flags0, flags1, blockIdx.x - L0WGS);
}

extern "C" void kernel_launch(void* const* d_in, const int* in_sizes, int n_in,
                              void* d_out, int out_size, void* d_ws, size_t ws_size,
                              hipStream_t stream) {
    const float* x   = (const float*)d_in[0];
    const float* W0f = (const float*)d_in[1];  const float* b0f = (const float*)d_in[2];
    const float* W0i = (const float*)d_in[3];  const float* b0i = (const float*)d_in[4];
    const float* W0c = (const float*)d_in[5];  const float* b0c = (const float*)d_in[6];
    const float* W0o = (const float*)d_in[7];  const float* b0o = (const float*)d_in[8];
    const float* W1f = (const float*)d_in[9];  const float* b1f = (const float*)d_in[10];
    const float* W1i = (const float*)d_in[11]; const float* b1i = (const float*)d_in[12];
    const float* W1c = (const float*)d_in[13]; const float* b1c = (const float*)d_in[14];
    const float* W1o = (const float*)d_in[15]; const float* b1o = (const float*)d_in[16];
    float* out = (float*)d_out;

    const size_t flag_bytes = (size_t)SEQ * FSTRIDE * 4;     // 64 KiB each
    const size_t ring_bytes = (size_t)SEQ * NB * HID * 2;    // 32 MiB each
    unsigned* flags0 = (unsigned*)d_ws;
    unsigned* flags1 = flags0 + SEQ * FSTRIDE;
    uint16_t* ring0  = (uint16_t*)((char*)d_ws + 2 * flag_bytes);
    uint16_t* ring1  = (uint16_t*)((char*)d_ws + 2 * flag_bytes + ring_bytes);
    const bool use_r1 = ws_size >= 2 * flag_bytes + 2 * ring_bytes;

    hipFuncSetAttribute((const void*)lstm_k<true>,
                        hipFuncAttributeMaxDynamicSharedMemorySize, SMEM_BYTES);
    hipFuncSetAttribute((const void*)lstm_k<false>,
                        hipFuncAttributeMaxDynamicSharedMemorySize, SMEM_BYTES);

    hipMemsetAsync(d_ws, 0, 2 * flag_bytes, stream);   // zero all flag bytes

    if (use_r1)
        hipLaunchKernelGGL(lstm_k<true>, dim3(NWG), dim3(256), SMEM_BYTES, stream,
            x, W0f, b0f, W0i, b0i, W0c, b0c, W0o, b0o,
            W1f, b1f, W1i, b1i, W1c, b1c, W1o, b1o,
            out, ring0, ring1, flags0, flags1);
    else
        hipLaunchKernelGGL(lstm_k<false>, dim3(NWG), dim3(256), SMEM_BYTES, stream,
            x, W0f, b0f, W0i, b0i, W0c, b0c, W0o, b0o,
            W1f, b1f, W1i, b1i, W1c, b1c, W1o, b1o,
            out, ring0, ring1, flags0, flags1);
}